// Round 17
// baseline (595.026 us; speedup 1.0000x reference)
//
#include <hip/hip_runtime.h>
#include <math.h>

#define N4    4096
#define FDIM  6
#define CC    1000
#define KP    1024
#define KP6   (6 * KP)
#define KNN   40
#define NRB   20
#define SSC   205

typedef __attribute__((ext_vector_type(8))) short bf16x8;
typedef __attribute__((ext_vector_type(4))) float f32x4;

__device__ __forceinline__ unsigned short f2bf(float f) {
    unsigned u = __float_as_uint(f);
    u = (u + 0x7fffu + ((u >> 16) & 1u)) >> 16;
    return (unsigned short)u;
}
__device__ __forceinline__ float bf2f(short s) {
    return __uint_as_float(((unsigned)(unsigned short)s) << 16);
}

// distance -> descending-sortable key (smaller d == larger key)
__device__ __forceinline__ unsigned d2key(float d) {
    unsigned u = __float_as_uint(d);
    return ((int)u < 0) ? u : (~u) ^ 0x80000000u;
}
__device__ __forceinline__ float key2d(unsigned k) {
    unsigned u = (k >> 31) ? k : (~k) ^ 0x80000000u;
    return __uint_as_float(u);
}

// async global->LDS, 16B per lane; LDS dest is wave-uniform base + lane*16
__device__ __forceinline__ void gload16(const unsigned short* g, short* l) {
    __builtin_amdgcn_global_load_lds(
        (const __attribute__((address_space(1))) unsigned int*)g,
        (__attribute__((address_space(3))) unsigned int*)l, 16, 0, 0);
}

// ---------------- graph build ----------------

__global__ __launch_bounds__(256) void sqx_kernel(const float* __restrict__ x,
                                                  float* __restrict__ sq1,
                                                  float* __restrict__ xhat) {
    int n = blockIdx.x * blockDim.x + threadIdx.x;
    if (n >= N4) return;
    float s = 0.f;
#pragma unroll
    for (int f = 0; f < FDIM; ++f) {
        float v = x[n * FDIM + f];
        s += v * v;
        xhat[n * 18 + f] = v;
    }
    sq1[n] = s;
}

// ---------------- radix top-40 on distance keys (exact) ----------------

#define NHC 4
#define HSTRIDE 257

struct TopkSh {
    unsigned sv[N4];                 // 16 KB keys
    int hist[NHC * HSTRIDE];         // 4.1 KB (4 copies: RL-flushed atomics are rare)
    int sc[256];                     // hist_pick scratch + equals strip counts
    float red[8];
    unsigned short cidx[N4];         // compacted indices
    unsigned short cv16[N4];         // compacted top-16 key bits (single-load scans)
    unsigned s_pfx;
    int s_need, s_cnt, s_m;
};

// zero scalars + histogram copies; call BEFORE key generation (which histograms inline)
__device__ __forceinline__ void topk_prep(TopkSh& sh, int t) {
    if (t == 0) { sh.s_pfx = 0u; sh.s_need = KNN; sh.s_cnt = 0; sh.s_m = 0; }
    for (int q = t; q < NHC * HSTRIDE; q += 512) sh.hist[q] = 0;
}

__device__ __forceinline__ void hist_pick(TopkSh& sh, int level, int t, int lane, int w, int nc) {
    if (t < 256) {
        int cnt = 0;
        for (int c = 0; c < nc; ++c) cnt += sh.hist[c * HSTRIDE + t];
        sh.sc[t] = cnt;
    }
    __syncthreads();
    if (w == 0) {
        int need = sh.s_need;
        unsigned pfx = sh.s_pfx;
        int c0 = sh.sc[4 * lane + 0], c1 = sh.sc[4 * lane + 1];
        int c2 = sh.sc[4 * lane + 2], c3 = sh.sc[4 * lane + 3];
        int s = c0 + c1 + c2 + c3;
        int suf = s;
#pragma unroll
        for (int off = 1; off < 64; off <<= 1) {
            int ov = __shfl_down(suf, off, 64);
            if (lane + off < 64) suf += ov;
        }
        int above = suf - s;
        int i3 = above + c3, i2 = i3 + c2, i1 = i2 + c1, i0 = i1 + c0;
        if (i3 >= need && i3 - c3 < need) { sh.s_need = need - (i3 - c3); sh.s_pfx = pfx | ((unsigned)(4 * lane + 3) << level); }
        if (i2 >= need && i2 - c2 < need) { sh.s_need = need - (i2 - c2); sh.s_pfx = pfx | ((unsigned)(4 * lane + 2) << level); }
        if (i1 >= need && i1 - c1 < need) { sh.s_need = need - (i1 - c1); sh.s_pfx = pfx | ((unsigned)(4 * lane + 1) << level); }
        if (i0 >= need && i0 - c0 < need) { sh.s_need = need - (i0 - c0); sh.s_pfx = pfx | ((unsigned)(4 * lane + 0) << level); }
    }
    __syncthreads();
}

// entry state: sv[] written, pass-1 (top byte) histograms accumulated by the caller.
// LASTLEVEL=0: full 32-bit refinement. LASTLEVEL=16: keys have constant low-16
// within a 16-bit prefix (bf16-derived): low16 = bit31 ? 0x0000 : 0xFFFF.
template<int LASTLEVEL>
__device__ void topk_core(TopkSh& sh, int n, int* __restrict__ idx,
                          float* __restrict__ val, float* __restrict__ rowsum) {
    int t = threadIdx.x, lane = t & 63, w = t >> 6;
    __syncthreads();
    hist_pick(sh, 24, t, lane, w, NHC);
    unsigned b1 = sh.s_pfx >> 24;

    // compact ALL tb >= b1 into cidx + cv16 (single ballot)
    for (int i = t; i < N4; i += 512) {
        unsigned u = sh.sv[i];
        bool isc = ((u >> 24) >= b1);
        unsigned long long mm = __ballot(isc);
        int cw = __popcll(mm);
        int base = 0;
        if (lane == 0 && cw) base = atomicAdd(&sh.s_m, cw);
        base = __shfl(base, 0);
        if (isc) {
            int p = base + __popcll(mm & ((1ull << lane) - 1ull));
            sh.cidx[p] = (unsigned short)i;
            sh.cv16[p] = (unsigned short)(u >> 16);
        }
    }
    __syncthreads();
    int mcnt = sh.s_m;

    // level 16: single-load scan over cv16
    for (int q = t; q < HSTRIDE; q += 512) sh.hist[q] = 0;
    __syncthreads();
    {
        unsigned pb = sh.s_pfx >> 24;
        for (int j = t; j < mcnt; j += 512) {
            unsigned v = sh.cv16[j];
            if ((v >> 8) == pb) atomicAdd(&sh.hist[v & 255], 1);
        }
    }
    __syncthreads();
    hist_pick(sh, 16, t, lane, w, 1);

    if (LASTLEVEL == 0) {
        // level 8: cv16 prefilter, dependent sv load only on 16-bit prefix match
        for (int q = t; q < HSTRIDE; q += 512) sh.hist[q] = 0;
        __syncthreads();
        {
            unsigned short p16 = (unsigned short)(sh.s_pfx >> 16);
            for (int j = t; j < mcnt; j += 512) {
                if (sh.cv16[j] == p16) {
                    unsigned u = sh.sv[sh.cidx[j]];
                    atomicAdd(&sh.hist[(u >> 8) & 255], 1);
                }
            }
        }
        __syncthreads();
        hist_pick(sh, 8, t, lane, w, 1);

        // level 0
        for (int q = t; q < HSTRIDE; q += 512) sh.hist[q] = 0;
        __syncthreads();
        {
            unsigned pfx = sh.s_pfx;
            unsigned short p16 = (unsigned short)(pfx >> 16);
            for (int j = t; j < mcnt; j += 512) {
                if (sh.cv16[j] == p16) {
                    unsigned u = sh.sv[sh.cidx[j]];
                    if ((u >> 8) == (pfx >> 8)) atomicAdd(&sh.hist[u & 255], 1);
                }
            }
        }
        __syncthreads();
        hist_pick(sh, 0, t, lane, w, 1);
    }

    unsigned Tbits = sh.s_pfx;
    if (LASTLEVEL == 16) Tbits |= (Tbits & 0x80000000u) ? 0u : 0xFFFFu;
    float Tf = __expf(-key2d(Tbits));
    int needEq = sh.s_need;

    // collect >T (cv16 prefilter; LASTLEVEL=16 reconstructs the full key from cv16)
    float psum = 0.f;
    unsigned short T16 = (unsigned short)(Tbits >> 16);
    for (int j = t; j < mcnt; j += 512) {
        unsigned short v = sh.cv16[j];
        if (v >= T16) {
            unsigned u;
            if (LASTLEVEL == 16)
                u = ((unsigned)v << 16) | ((v & 0x8000u) ? 0u : 0xFFFFu);
            else
                u = sh.sv[sh.cidx[j]];
            if (u > Tbits) {
                int p = atomicAdd(&sh.s_cnt, 1);
                float fv = __expf(-key2d(u));
                idx[(size_t)n * KNN + p] = (int)sh.cidx[j];
                val[(size_t)n * KNN + p] = fv;
                psum += fv;
            }
        }
    }
    // wave-level reduce, then 8 partials
#pragma unroll
    for (int o = 32; o; o >>= 1) psum += __shfl_down(psum, o);
    if (lane == 0) sh.red[w] = psum;
    __syncthreads();
    if (t == 0) {
        float s = 0.f;
#pragma unroll
        for (int q = 0; q < 8; ++q) s += sh.red[q];
        rowsum[n] = s + (float)needEq * Tf;
    }

    // equals: earliest indices first, strip-parallel across the 8 waves
    {
        int filled0 = KNN - needEq;
        int base_i = w * 512;
        int cnt = 0;
#pragma unroll
        for (int q = 0; q < 8; ++q) {
            bool eq = (sh.sv[base_i + q * 64 + lane] == Tbits);
            cnt += __popcll(__ballot(eq));
        }
        if (lane == 0) sh.sc[w] = cnt;
        __syncthreads();
        int pre = 0;
        for (int q = 0; q < w; ++q) pre += sh.sc[q];
        if (pre < needEq) {
            int run = pre;
            for (int q = 0; q < 8 && run < needEq; ++q) {
                bool eq = (sh.sv[base_i + q * 64 + lane] == Tbits);
                unsigned long long m = __ballot(eq);
                int lpre = __popcll(m & ((1ull << lane) - 1ull));
                if (eq && run + lpre < needEq) {
                    idx[(size_t)n * KNN + filled0 + run + lpre] = base_i + q * 64 + lane;
                    val[(size_t)n * KNN + filled0 + run + lpre] = Tf;
                }
                run += __popcll(m);
            }
        }
    }
}

__global__ __launch_bounds__(512) void topk_fused1(const float* __restrict__ x,
                                                   const float* __restrict__ sq1,
                                                   int* __restrict__ idx, float* __restrict__ val,
                                                   float* __restrict__ rowsum) {
    __shared__ TopkSh sh;
    __shared__ float xn[FDIM];
    __shared__ float sns;
    int n = blockIdx.x;
    int t = threadIdx.x;
    if (t < FDIM) xn[t] = x[n * FDIM + t];
    if (t == FDIM) sns = sq1[n];
    topk_prep(sh, t);
    __syncthreads();
    float x0 = xn[0], x1 = xn[1], x2 = xn[2], x3 = xn[3], x4 = xn[4], x5 = xn[5];
    float sn = sns;
    int* hw = &sh.hist[(t & 3) * HSTRIDE];
    unsigned prevb = 0xFFFFFFFFu; int rl = 0;
    for (int i = t; i < N4; i += 512) {
        const float2* xi = (const float2*)(x + i * FDIM);
        float2 p0 = xi[0], p1 = xi[1], p2 = xi[2];
        float d = x0 * p0.x + x1 * p0.y + x2 * p1.x + x3 * p1.y + x4 * p2.x + x5 * p2.y;
        float e = sn + sq1[i] - 2.f * d;
        unsigned k = d2key(e);
        sh.sv[i] = k;
        unsigned b = k >> 24;
        if (b == prevb) ++rl;
        else { if (rl) atomicAdd(&hw[prevb], rl); prevb = b; rl = 1; }
    }
    if (rl) atomicAdd(&hw[prevb], rl);
    topk_core<0>(sh, n, idx, val, rowsum);
}

// graph-2: reads precomputed bf16 distance row; keys are 16-bit-exact
__global__ __launch_bounds__(512) void topk_radix(const unsigned short* __restrict__ S,
                                                  int* __restrict__ idx, float* __restrict__ val,
                                                  float* __restrict__ rowsum) {
    __shared__ TopkSh sh;
    int n = blockIdx.x;
    int t = threadIdx.x;
    topk_prep(sh, t);
    const unsigned short* row = S + (size_t)n * N4;
    bf16x8 a = *(const bf16x8*)(row + 8 * t);
    __syncthreads();
    int* hw = &sh.hist[(t & 3) * HSTRIDE];
    unsigned prevb = 0xFFFFFFFFu; int rl = 0;
#pragma unroll
    for (int q = 0; q < 8; ++q) {
        unsigned k = d2key(bf2f(a[q]));
        sh.sv[8 * t + q] = k;
        unsigned b = k >> 24;
        if (b == prevb) ++rl;
        else { if (rl) atomicAdd(&hw[prevb], rl); prevb = b; rl = 1; }
    }
    if (rl) atomicAdd(&hw[prevb], rl);
    topk_core<16>(sh, n, idx, val, rowsum);
}

// wnorm with inline rsqrt; rs = row sums
__global__ __launch_bounds__(256) void wnorm_kernel(float* __restrict__ wv,
                                                    const int* __restrict__ idx,
                                                    const float* __restrict__ rs) {
    int i = blockIdx.x * 256 + threadIdx.x;
    if (i >= N4 * KNN) return;
    int n = i / KNN;
    wv[i] = wv[i] * rsqrtf(rs[n]) * rsqrtf(rs[idx[i]]);
}

// Tn[n,:] = a*(Tc[n,:] - sum_j wv[n,j]*Tc[idx[n,j],:]) - b*Tp[n,:]
// dense mapping: 42 nodes/block x F=6 cols = 252 active threads (was 4096 blocks x 6/64 lanes)
#define SNPB 42
__global__ __launch_bounds__(256) void spmv_cheb(const float* __restrict__ Tc,
                                                 const float* __restrict__ Tp,
                                                 float* __restrict__ Tn,
                                                 const int* __restrict__ idx,
                                                 const float* __restrict__ wv,
                                                 int sC, int sP, int sN,
                                                 float a, float b) {
    __shared__ int   si[SNPB * KNN];
    __shared__ float sw[SNPB * KNN];
    int t = threadIdx.x;
    int nbase = blockIdx.x * SNPB;
    int nmax = N4 - nbase; if (nmax > SNPB) nmax = SNPB;
    for (int i = t; i < nmax * KNN; i += 256) {
        int ln = i / KNN, j = i % KNN;
        si[ln * KNN + j] = idx[(size_t)(nbase + ln) * KNN + j];
        sw[ln * KNN + j] = wv[(size_t)(nbase + ln) * KNN + j];
    }
    __syncthreads();
    int ln = t / FDIM, c = t % FDIM;
    if (ln >= nmax || t >= SNPB * FDIM) return;
    int n = nbase + ln;
    const int*   sip = &si[ln * KNN];
    const float* swp = &sw[ln * KNN];
    float s = 0.f;
#pragma unroll 8
    for (int j = 0; j < KNN; ++j) s += swp[j] * Tc[(size_t)sip[j] * sC + c];
    float v = a * (Tc[(size_t)n * sC + c] - s);
    if (b != 0.f) v -= b * Tp[(size_t)n * sP + c];
    Tn[(size_t)n * sN + c] = v;
}

// bf16-resident recursion over Tall slices (row stride KP6).
// grid (N4, 2): blockIdx.y = column half (slow dispatch dim) -> per-phase gather
// working set 4 MB -> fits per-XCD L2 (8 MB slice did not).
__global__ __launch_bounds__(256) void spmv_cheb_bf(const unsigned short* __restrict__ Tcbf,
                                                    const unsigned short* __restrict__ Tpbf,
                                                    unsigned short* __restrict__ Tnbf,
                                                    const int* __restrict__ idx,
                                                    const float* __restrict__ wv,
                                                    float a, float b) {
    __shared__ int   si[KNN];
    __shared__ float sw[KNN];
    __shared__ float part[3][64][9];   // +1 pad breaks write-bank aliasing
    int n = blockIdx.x;
    int t = threadIdx.x;
    int tt = t & 63, g = t >> 6;       // 64 col-groups x 4 neighbor-groups of 10
    if (t < KNN) {
        si[t] = idx[(size_t)n * KNN + t];
        sw[t] = wv[(size_t)n * KNN + t];
    }
    __syncthreads();
    int c = blockIdx.y * 512 + tt * 8;
    float acc0 = 0, acc1 = 0, acc2 = 0, acc3 = 0, acc4 = 0, acc5 = 0, acc6 = 0, acc7 = 0;
    int j0 = g * 10;
#pragma unroll
    for (int j = j0; j < j0 + 10; ++j) {
        bf16x8 v = *(const bf16x8*)(Tcbf + (size_t)si[j] * KP6 + c);
        float wj = sw[j];
        acc0 += wj * bf2f(v[0]); acc1 += wj * bf2f(v[1]);
        acc2 += wj * bf2f(v[2]); acc3 += wj * bf2f(v[3]);
        acc4 += wj * bf2f(v[4]); acc5 += wj * bf2f(v[5]);
        acc6 += wj * bf2f(v[6]); acc7 += wj * bf2f(v[7]);
    }
    if (g) {
        float* p = part[g - 1][tt];
        p[0] = acc0; p[1] = acc1; p[2] = acc2; p[3] = acc3;
        p[4] = acc4; p[5] = acc5; p[6] = acc6; p[7] = acc7;
    }
    __syncthreads();
    if (g == 0) {
#pragma unroll
        for (int pg = 0; pg < 3; ++pg) {
            const float* p = part[pg][tt];
            acc0 += p[0]; acc1 += p[1]; acc2 += p[2]; acc3 += p[3];
            acc4 += p[4]; acc5 += p[5]; acc6 += p[6]; acc7 += p[7];
        }
        bf16x8 tc = *(const bf16x8*)(Tcbf + (size_t)n * KP6 + c);
        float o0 = a * (bf2f(tc[0]) - acc0), o1 = a * (bf2f(tc[1]) - acc1);
        float o2 = a * (bf2f(tc[2]) - acc2), o3 = a * (bf2f(tc[3]) - acc3);
        float o4 = a * (bf2f(tc[4]) - acc4), o5 = a * (bf2f(tc[5]) - acc5);
        float o6 = a * (bf2f(tc[6]) - acc6), o7 = a * (bf2f(tc[7]) - acc7);
        if (b != 0.f) {
            bf16x8 tp = *(const bf16x8*)(Tpbf + (size_t)n * KP6 + c);
            o0 -= b * bf2f(tp[0]); o1 -= b * bf2f(tp[1]);
            o2 -= b * bf2f(tp[2]); o3 -= b * bf2f(tp[3]);
            o4 -= b * bf2f(tp[4]); o5 -= b * bf2f(tp[5]);
            o6 -= b * bf2f(tp[6]); o7 -= b * bf2f(tp[7]);
        }
        bf16x8 ob;
        ob[0] = (short)f2bf(o0); ob[1] = (short)f2bf(o1);
        ob[2] = (short)f2bf(o2); ob[3] = (short)f2bf(o3);
        ob[4] = (short)f2bf(o4); ob[5] = (short)f2bf(o5);
        ob[6] = (short)f2bf(o6); ob[7] = (short)f2bf(o7);
        *(bf16x8*)(Tnbf + (size_t)n * KP6 + c) = ob;
    }
}

// W2 [6*CC x CC] fp32 -> W2T6 [1024 rows(n)][KP6 cols(k)] bf16; vectorized bf16x8 stores
__global__ __launch_bounds__(256) void w2t_kernel(const float* __restrict__ W2,
                                                  unsigned short* __restrict__ out) {
    __shared__ unsigned short tile[64][65];
    int t = threadIdx.x;
    int k0 = blockIdx.x * 64, n0 = blockIdx.y * 64, s = blockIdx.z;
#pragma unroll
    for (int p = 0; p < 16; ++p) {
        int i = p * 256 + t;
        int kk = i >> 6, nn = i & 63;
        int k = k0 + kk, n = n0 + nn;
        float v = (k < CC && n < CC) ? W2[((size_t)s * CC + k) * CC + n] : 0.f;
        tile[kk][nn] = f2bf(v);
    }
    __syncthreads();
#pragma unroll
    for (int p = 0; p < 2; ++p) {
        int i = p * 256 + t;          // 512 chunks: 64 rows(nn) x 8 k-chunks
        int nn = i >> 3, kk = (i & 7) * 8;
        bf16x8 v;
#pragma unroll
        for (int j = 0; j < 8; ++j) v[j] = (short)tile[kk + j][nn];
        *(bf16x8*)(out + (size_t)(n0 + nn) * KP6 + (size_t)s * KP + k0 + kk) = v;
    }
}

// ---------------- MFMA GEMM cores ----------------

#define LDT 32                      // linear LDS tile pitch (shorts)
#define SP2 136                     // 128-tile epilogue staging pitch
#define SP 264                      // 256-tile epilogue staging pitch
#define ABUF (128 * LDT)            // one [128][32] tile (shorts)
#define BBUF (256 * LDT)            // one [256][32] tile (shorts)

// 128x128-tile core, BK=64: two linear [128][32] k-half tiles per matrix,
// single-buffer, 2 barriers per BK64 step (measured good: round 8, 62 us).
template<int STR>
__device__ __forceinline__ void gemm_core128_bk64(const unsigned short* __restrict__ Ag,
                                                  const unsigned short* __restrict__ Bg,
                                                  short* sm, int t,
                                                  int kbeg, int kend,
                                                  f32x4 (&acc)[4][4]) {
    int l = t & 63, w = t >> 6;
    int wm = (w >> 1) * 64, wn = (w & 1) * 64;
    int lr = l & 15, lq8 = (l >> 4) * 8;
    short* A0 = sm;
    short* A1 = sm + ABUF;
    short* B0 = sm + 2 * ABUF;
    short* B1 = sm + 3 * ABUF;
    // staging: one gload16 covers 16 rows x 32 cols; lane l -> row +(l>>2), col (l&3)*8
    // LDS lands linear: (l>>2)*32 + (l&3)*8 == 8*l
    size_t ga0 = (size_t)(32 * w + (l >> 2)) * STR + (l & 3) * 8;
    size_t ga1 = ga0 + (size_t)16 * STR;
    int lo = (32 * w) * LDT;
    for (int k0 = kbeg; k0 < kend; k0 += 64) {
        gload16(Ag + ga0 + k0,      A0 + lo);
        gload16(Ag + ga1 + k0,      A0 + lo + 16 * LDT);
        gload16(Ag + ga0 + k0 + 32, A1 + lo);
        gload16(Ag + ga1 + k0 + 32, A1 + lo + 16 * LDT);
        gload16(Bg + ga0 + k0,      B0 + lo);
        gload16(Bg + ga1 + k0,      B0 + lo + 16 * LDT);
        gload16(Bg + ga0 + k0 + 32, B1 + lo);
        gload16(Bg + ga1 + k0 + 32, B1 + lo + 16 * LDT);
        __syncthreads();
        bf16x8 af[4], bfr[4];
#pragma unroll
        for (int mi = 0; mi < 4; ++mi)
            af[mi] = *(const bf16x8*)&A0[(wm + mi * 16 + lr) * LDT + lq8];
#pragma unroll
        for (int ni = 0; ni < 4; ++ni)
            bfr[ni] = *(const bf16x8*)&B0[(wn + ni * 16 + lr) * LDT + lq8];
#pragma unroll
        for (int mi = 0; mi < 4; ++mi)
#pragma unroll
            for (int ni = 0; ni < 4; ++ni)
                acc[mi][ni] = __builtin_amdgcn_mfma_f32_16x16x32_bf16(af[mi], bfr[ni], acc[mi][ni], 0, 0, 0);
#pragma unroll
        for (int mi = 0; mi < 4; ++mi)
            af[mi] = *(const bf16x8*)&A1[(wm + mi * 16 + lr) * LDT + lq8];
#pragma unroll
        for (int ni = 0; ni < 4; ++ni)
            bfr[ni] = *(const bf16x8*)&B1[(wn + ni * 16 + lr) * LDT + lq8];
#pragma unroll
        for (int mi = 0; mi < 4; ++mi)
#pragma unroll
            for (int ni = 0; ni < 4; ++ni)
                acc[mi][ni] = __builtin_amdgcn_mfma_f32_16x16x32_bf16(af[mi], bfr[ni], acc[mi][ni], 0, 0, 0);
        __syncthreads();
    }
}

// batched cheb2 GEMM: bf16 partials, 128x128 tiles, BK=64, split-K=3
// grid (32 m, 8 n, 3 z) -- measured-good round-8 config (62 us)
__global__ __launch_bounds__(256) void gemm_mfma_big(const unsigned short* __restrict__ A,
                                                     const unsigned short* __restrict__ B,
                                                     unsigned short* __restrict__ Cp) {
    __shared__ short smem[4 * ABUF];   // A0,A1,B0,B1 = 32 KB
    int t = threadIdx.x;
    int m0 = blockIdx.x * 128, n0 = blockIdx.y * 128;
    int kz = blockIdx.z;
    unsigned short* C = Cp + (size_t)kz * N4 * CC;
    f32x4 acc[4][4] = {};
    gemm_core128_bk64<KP6>(A + (size_t)m0 * KP6, B + (size_t)n0 * KP6, smem, t,
                           kz * 2 * KP, kz * 2 * KP + 2 * KP, acc);
    int l = t & 63, w = t >> 6;
    int wn = (w & 1) * 64;
    int lr = l & 15, lq4 = (l >> 4) * 4;
    int lrow = (w >> 1) * 16 + lq4;
#pragma unroll
    for (int mi = 0; mi < 4; ++mi) {
        __syncthreads();
#pragma unroll
        for (int ni = 0; ni < 4; ++ni) {
            int col = wn + ni * 16 + lr;
            f32x4 v = acc[mi][ni];
#pragma unroll
            for (int r = 0; r < 4; ++r) smem[(lrow + r) * SP2 + col] = (short)f2bf(v[r]);
        }
        __syncthreads();
#pragma unroll
        for (int q = 0; q < 2; ++q) {
            int row = q * 16 + (t >> 4);
            int col = (t & 15) * 8;
            int gm = m0 + (row >> 4) * 64 + mi * 16 + (row & 15);
            int gn = n0 + col;
            if (gn < CC) {
                bf16x8 vv = *(bf16x8*)&smem[row * SP2 + col];
                *(bf16x8*)(C + (size_t)gm * CC + gn) = vv;
            }
        }
    }
}

// out2 = relu(sum_z bf16 Cz + b2) -> fp32 out  (3 split-K slices)
__global__ __launch_bounds__(256) void bias_relu_merge(const unsigned short* __restrict__ Cp,
                                                       const float* __restrict__ b2,
                                                       float* __restrict__ out2) {
    size_t i8 = (size_t)blockIdx.x * 256 + threadIdx.x;
    if (i8 >= (size_t)N4 * CC / 8) return;
    size_t i = i8 * 8;
    int c = (int)(i % CC);
    const size_t S = (size_t)N4 * CC;
    float s[8] = {};
#pragma unroll
    for (int z = 0; z < 3; ++z) {
        bf16x8 v = *(const bf16x8*)(Cp + z * S + i);
#pragma unroll
        for (int q = 0; q < 8; ++q) s[q] += bf2f(v[q]);
    }
    float4 o0, o1;
    o0.x = fmaxf(s[0] + b2[c + 0], 0.f); o0.y = fmaxf(s[1] + b2[c + 1], 0.f);
    o0.z = fmaxf(s[2] + b2[c + 2], 0.f); o0.w = fmaxf(s[3] + b2[c + 3], 0.f);
    o1.x = fmaxf(s[4] + b2[c + 4], 0.f); o1.y = fmaxf(s[5] + b2[c + 5], 0.f);
    o1.z = fmaxf(s[6] + b2[c + 6], 0.f); o1.w = fmaxf(s[7] + b2[c + 7], 0.f);
    *(float4*)(out2 + i) = o0;
    *(float4*)(out2 + i + 4) = o1;
}

// gram over Tall slice 0 -> bf16 distances, 128x256 tiles, BK=64 single-buffer
__global__ __launch_bounds__(256, 2) void gram2_mfma(const unsigned short* __restrict__ Tall,
                                                     const float* __restrict__ sq2,
                                                     unsigned short* __restrict__ S) {
    __shared__ short smem[2 * ABUF + 2 * BBUF];   // A0,A1,B0,B1 = 48 KB
    int t = threadIdx.x;
    int m0 = blockIdx.x * 128, n0 = blockIdx.y * 256;
    int l = t & 63, w = t >> 6;
    int wm = (w >> 1) * 64, wn = (w & 1) * 128;
    int lr = l & 15, lq8 = (l >> 4) * 8;
    short* A0 = smem;
    short* A1 = smem + ABUF;
    short* B0 = smem + 2 * ABUF;
    short* B1 = smem + 2 * ABUF + BBUF;
    const unsigned short* Ag = Tall + (size_t)m0 * KP6;
    const unsigned short* Bg = Tall + (size_t)n0 * KP6;
    // A: wave w covers rows [32w,32w+32) via 2 issues; B: rows [64w,64w+64) via 4 issues
    size_t gaA = (size_t)(32 * w + (l >> 2)) * KP6 + (l & 3) * 8;
    size_t gaB = (size_t)(64 * w + (l >> 2)) * KP6 + (l & 3) * 8;
    int loA = (32 * w) * LDT;
    int loB = (64 * w) * LDT;
    f32x4 acc[4][8] = {};
    for (int k0 = 0; k0 < KP; k0 += 64) {
        gload16(Ag + gaA + k0,                         A0 + loA);
        gload16(Ag + gaA + (size_t)16 * KP6 + k0,      A0 + loA + 16 * LDT);
        gload16(Ag + gaA + k0 + 32,                    A1 + loA);
        gload16(Ag + gaA + (size_t)16 * KP6 + k0 + 32, A1 + loA + 16 * LDT);
#pragma unroll
        for (int r = 0; r < 4; ++r) {
            gload16(Bg + gaB + (size_t)(16 * r) * KP6 + k0,      B0 + loB + 16 * r * LDT);
            gload16(Bg + gaB + (size_t)(16 * r) * KP6 + k0 + 32, B1 + loB + 16 * r * LDT);
        }
        __syncthreads();
        bf16x8 af[4], bfr[8];
#pragma unroll
        for (int mi = 0; mi < 4; ++mi)
            af[mi] = *(const bf16x8*)&A0[(wm + mi * 16 + lr) * LDT + lq8];
#pragma unroll
        for (int ni = 0; ni < 8; ++ni)
            bfr[ni] = *(const bf16x8*)&B0[(wn + ni * 16 + lr) * LDT + lq8];
#pragma unroll
        for (int mi = 0; mi < 4; ++mi)
#pragma unroll
            for (int ni = 0; ni < 8; ++ni)
                acc[mi][ni] = __builtin_amdgcn_mfma_f32_16x16x32_bf16(af[mi], bfr[ni], acc[mi][ni], 0, 0, 0);
#pragma unroll
        for (int mi = 0; mi < 4; ++mi)
            af[mi] = *(const bf16x8*)&A1[(wm + mi * 16 + lr) * LDT + lq8];
#pragma unroll
        for (int ni = 0; ni < 8; ++ni)
            bfr[ni] = *(const bf16x8*)&B1[(wn + ni * 16 + lr) * LDT + lq8];
#pragma unroll
        for (int mi = 0; mi < 4; ++mi)
#pragma unroll
            for (int ni = 0; ni < 8; ++ni)
                acc[mi][ni] = __builtin_amdgcn_mfma_f32_16x16x32_bf16(af[mi], bfr[ni], acc[mi][ni], 0, 0, 0);
        __syncthreads();
    }
    int lq4 = (l >> 4) * 4;
    int lrow = (w >> 1) * 16 + lq4;
#pragma unroll
    for (int mi = 0; mi < 4; ++mi) {
        __syncthreads();
        int mbase = m0 + (w >> 1) * 64 + mi * 16 + lq4;
#pragma unroll
        for (int ni = 0; ni < 8; ++ni) {
            int col = wn + ni * 16 + lr;
            float sn = sq2[n0 + col];
            f32x4 v = acc[mi][ni];
#pragma unroll
            for (int r = 0; r < 4; ++r)
                smem[(lrow + r) * SP + col] = (short)f2bf(sq2[mbase + r] + sn - 2.f * v[r]);
        }
        __syncthreads();
#pragma unroll
        for (int q = 0; q < 4; ++q) {
            int row = q * 8 + (t >> 5);
            int col = (t & 31) * 8;
            int gm = m0 + (row >> 4) * 64 + mi * 16 + (row & 15);
            int gn = n0 + col;
            bf16x8 vv = *(bf16x8*)&smem[row * SP + col];
            *(bf16x8*)(S + (size_t)gm * N4 + gn) = vv;
        }
    }
}

// ---------------- cheb conv 1 (fused: outF fp32 + Tall slice-0 bf16 + sq2 rowsums) ----------------

__global__ __launch_bounds__(256) void cheb1_out_kernel(const float* __restrict__ xhat,
                                                        const float* __restrict__ W1,
                                                        const float* __restrict__ b1,
                                                        float* __restrict__ outF,
                                                        unsigned short* __restrict__ tall,
                                                        float* __restrict__ sq2) {
    __shared__ float xh[16][18];
    __shared__ float wred[4][16];
    int n0 = blockIdx.x * 16;
    int tid = threadIdx.x;
    for (int i = tid; i < 16 * 18; i += 256) xh[i / 18][i % 18] = xhat[(size_t)n0 * 18 + i];
    __syncthreads();
    float ps[16];
#pragma unroll
    for (int r = 0; r < 16; ++r) ps[r] = 0.f;
    for (int c0 = 0; c0 < KP; c0 += 256) {
        int c = c0 + tid;
        if (c < CC) {
            float acc[16];
#pragma unroll
            for (int r = 0; r < 16; ++r) acc[r] = 0.f;
            for (int f = 0; f < 18; ++f) {
                float wv = W1[(size_t)f * CC + c];
#pragma unroll
                for (int r = 0; r < 16; ++r) acc[r] += xh[r][f] * wv;
            }
            float bb = b1[c];
#pragma unroll
            for (int r = 0; r < 16; ++r) {
                float v = fmaxf(acc[r] + bb, 0.f);
                outF[(size_t)(n0 + r) * CC + c] = v;
                tall[(size_t)(n0 + r) * KP6 + c] = f2bf(v);
                ps[r] += v * v;
            }
        } else {   // zero-pad Tall cols [CC, KP)
#pragma unroll
            for (int r = 0; r < 16; ++r)
                tall[(size_t)(n0 + r) * KP6 + c] = 0;
        }
    }
    // reduce ps across 256 threads: per-wave shfl, then 4-way LDS combine
    int lane = tid & 63, w = tid >> 6;
#pragma unroll
    for (int r = 0; r < 16; ++r) {
        float s = ps[r];
#pragma unroll
        for (int o = 32; o; o >>= 1) s += __shfl_down(s, o);
        if (lane == 0) wred[w][r] = s;
    }
    __syncthreads();
    if (tid < 16)
        sq2[n0 + tid] = wred[0][tid] + wred[1][tid] + wred[2][tid] + wred[3][tid];
}

// ---------------- regs (frobenius of O^T @ T) ----------------

__global__ __launch_bounds__(256) void matT6_partial(const float* __restrict__ O,
                                                     const float* __restrict__ T, int ts,
                                                     float* __restrict__ M) {
    __shared__ float sT[128][6];
    int t = threadIdx.x;
    int c = blockIdx.x * 256 + t;
    int n0 = blockIdx.y * 128;
    for (int i = t; i < 128 * 6; i += 256) {
        int nn = i / 6, f = i % 6;
        sT[nn][f] = T[(size_t)(n0 + nn) * ts + f];
    }
    __syncthreads();
    if (c >= CC) return;
    float a0 = 0, a1 = 0, a2 = 0, a3 = 0, a4 = 0, a5 = 0;
    for (int nn = 0; nn < 128; ++nn) {
        float o = O[(size_t)(n0 + nn) * CC + c];
        a0 += o * sT[nn][0]; a1 += o * sT[nn][1]; a2 += o * sT[nn][2];
        a3 += o * sT[nn][3]; a4 += o * sT[nn][4]; a5 += o * sT[nn][5];
    }
    atomicAdd(&M[0 * CC + c], a0);
    atomicAdd(&M[1 * CC + c], a1);
    atomicAdd(&M[2 * CC + c], a2);
    atomicAdd(&M[3 * CC + c], a3);
    atomicAdd(&M[4 * CC + c], a4);
    atomicAdd(&M[5 * CC + c], a5);
}

// matT6 + per-column max in one pass over O (used for the out2 pass; dst zeroed, O >= 0)
__global__ __launch_bounds__(256) void matT6_colmax(const float* __restrict__ O,
                                                    const float* __restrict__ T, int ts,
                                                    float* __restrict__ M,
                                                    float* __restrict__ dst) {
    __shared__ float sT[128][6];
    int t = threadIdx.x;
    int c = blockIdx.x * 256 + t;
    int n0 = blockIdx.y * 128;
    for (int i = t; i < 128 * 6; i += 256) {
        int nn = i / 6, f = i % 6;
        sT[nn][f] = T[(size_t)(n0 + nn) * ts + f];
    }
    __syncthreads();
    if (c >= CC) return;
    float a0 = 0, a1 = 0, a2 = 0, a3 = 0, a4 = 0, a5 = 0;
    float mx = 0.f;
    for (int nn = 0; nn < 128; ++nn) {
        float o = O[(size_t)(n0 + nn) * CC + c];
        a0 += o * sT[nn][0]; a1 += o * sT[nn][1]; a2 += o * sT[nn][2];
        a3 += o * sT[nn][3]; a4 += o * sT[nn][4]; a5 += o * sT[nn][5];
        mx = fmaxf(mx, o);
    }
    atomicAdd(&M[0 * CC + c], a0);
    atomicAdd(&M[1 * CC + c], a1);
    atomicAdd(&M[2 * CC + c], a2);
    atomicAdd(&M[3 * CC + c], a3);
    atomicAdd(&M[4 * CC + c], a4);
    atomicAdd(&M[5 * CC + c], a5);
    atomicMax((int*)&dst[c], __float_as_int(mx));
}

__global__ __launch_bounds__(256) void fro_kernel(const float* __restrict__ M, float* __restrict__ dst) {
    __shared__ float red[256];
    int t = threadIdx.x;
    int i = blockIdx.x * 256 + t;
    float v = (i < 6 * CC) ? M[i] : 0.f;
    red[t] = v * v;
    __syncthreads();
    for (int o = 128; o; o >>= 1) { if (t < o) red[t] += red[t + o]; __syncthreads(); }
    if (t == 0) atomicAdd(dst, red[0]);
}

// ---------------- pooling ----------------

__global__ __launch_bounds__(256) void vfr_kernel(const float* __restrict__ outF,
                                                  const int* __restrict__ sccs,
                                                  float* __restrict__ vfr) {
    int r = blockIdx.y;
    int c = blockIdx.x * 256 + threadIdx.x;
    if (c >= CC) return;
    int s0 = blockIdx.z * 41;
    float m = 0.f;
    for (int s = s0; s < s0 + 41; ++s) {
        int n = sccs[r * SSC + s];
        m = fmaxf(m, outF[(size_t)n * CC + c]);
    }
    atomicMax((int*)&vfr[(size_t)r * CC + c], __float_as_int(m));
}

// ---------------- reeb branch ----------------

__global__ __launch_bounds__(256) void reeb_mm_kernel(const float* __restrict__ Lr,
                                                      const float* __restrict__ Vin,
                                                      const float* __restrict__ Vsub,
                                                      float* __restrict__ Vout, float a2) {
    int c = blockIdx.x * 256 + threadIdx.x;
    if (c >= CC) return;
    int r = blockIdx.y;
    float s = 0.f;
#pragma unroll
    for (int j = 0; j < NRB; ++j) s += Lr[r * NRB + j] * Vin[(size_t)j * CC + c];
    float v = a2 * s;
    if (Vsub) v -= Vsub[(size_t)r * CC + c];
    Vout[(size_t)r * CC + c] = v;
}

#define RKC 25
__global__ __launch_bounds__(256) void reeb_conv_splitk(const float* __restrict__ vfr,
                                                        const float* __restrict__ tr1,
                                                        const float* __restrict__ tr2,
                                                        const float* __restrict__ Wr,
                                                        float* __restrict__ rpre) {
    __shared__ float sA[NRB][RKC];
    int t = threadIdx.x;
    int kbase = blockIdx.y * RKC;
    for (int i = t; i < NRB * RKC; i += 256) {
        int r = i / RKC, kk = i % RKC;
        int kg = kbase + kk;
        float v;
        if (kg < CC)           v = vfr[(size_t)r * CC + kg];
        else if (kg < 2 * CC)  v = tr1[(size_t)r * CC + kg - CC];
        else                   v = tr2[(size_t)r * CC + kg - 2 * CC];
        sA[r][kk] = v;
    }
    __syncthreads();
    int c = blockIdx.x * 256 + t;
    if (c >= CC) return;
    float acc[NRB];
#pragma unroll
    for (int r = 0; r < NRB; ++r) acc[r] = 0.f;
    for (int kk = 0; kk < RKC; ++kk) {
        float wv = Wr[(size_t)(kbase + kk) * CC + c];
#pragma unroll
        for (int r = 0; r < NRB; ++r) acc[r] += sA[r][kk] * wv;
    }
#pragma unroll
    for (int r = 0; r < NRB; ++r) atomicAdd(&rpre[(size_t)r * CC + c], acc[r]);
}

__global__ __launch_bounds__(256) void reeb_max_kernel(const float* __restrict__ pre,
                                                       const float* __restrict__ br,
                                                       float* __restrict__ rbm) {
    int c = blockIdx.x * 256 + threadIdx.x;
    if (c >= CC) return;
    float bb = br[c];
    float m = 0.f;
    for (int r = 0; r < NRB; ++r) m = fmaxf(m, fmaxf(pre[(size_t)r * CC + c] + bb, 0.f));
    rbm[c] = m;
}

// ---------------- FC head ----------------

__global__ __launch_bounds__(256) void fc1_kernel(const float* __restrict__ rbm,
                                                  const float* __restrict__ otm,
                                                  const float* __restrict__ w,
                                                  float* __restrict__ h1pre) {
    int j = blockIdx.x * 256 + threadIdx.x;
    if (j >= 512) return;
    int i0 = blockIdx.y * 250;
    float s = 0.f;
    for (int i = i0; i < i0 + 250; ++i) {
        float v = (i < CC) ? rbm[i] : otm[i - CC];
        s += v * w[(size_t)i * 512 + j];
    }
    atomicAdd(&h1pre[j], s);
}

__global__ __launch_bounds__(512) void fc23_kernel(const float* __restrict__ h1pre,
                                                   const float* __restrict__ b1f,
                                                   const float* __restrict__ w2,
                                                   const float* __restrict__ b2f,
                                                   const float* __restrict__ w3,
                                                   const float* __restrict__ b3f,
                                                   float* __restrict__ dout) {
    __shared__ float h1[512];
    __shared__ float h2[128];
    int t = threadIdx.x;
    h1[t] = fmaxf(h1pre[t] + b1f[t], 0.f);
    __syncthreads();
    if (t < 128) {
        float s = b2f[t];
        for (int i = 0; i < 512; ++i) s += h1[i] * w2[(size_t)i * 128 + t];
        h2[t] = fmaxf(s, 0.f);
    }
    __syncthreads();
    if (t < 40) {
        float s = b3f[t];
        for (int i = 0; i < 128; ++i) s += h2[i] * w3[(size_t)i * 40 + t];
        dout[t] = s;
    }
}

__global__ __launch_bounds__(256) void finalize_kernel(const float* __restrict__ racc,
                                                       const float* __restrict__ f1w,
                                                       const float* __restrict__ f1b,
                                                       const float* __restrict__ f2w,
                                                       const float* __restrict__ f2b,
                                                       const float* __restrict__ f3w,
                                                       const float* __restrict__ f3b,
                                                       float* __restrict__ dout) {
    __shared__ float red[256];
    __shared__ float res[3];
    int t = threadIdx.x;
    float s1 = 0.f, s2 = 0.f, s3 = 0.f;
    for (int i = t; i < 2000; i += 256) { float v = f1w[(size_t)i * 512]; s1 += v * v; }
    for (int i = t; i < 512; i += 256) { float v = f2w[(size_t)i * 128]; s2 += v * v; }
    if (t < 128) { float v = f3w[(size_t)t * 40]; s3 = v * v; }

    red[t] = s1; __syncthreads();
    for (int o = 128; o; o >>= 1) { if (t < o) red[t] += red[t + o]; __syncthreads(); }
    if (t == 0) res[0] = red[0];
    __syncthreads();
    red[t] = s2; __syncthreads();
    for (int o = 128; o; o >>= 1) { if (t < o) red[t] += red[t + o]; __syncthreads(); }
    if (t == 0) res[1] = red[0];
    __syncthreads();
    red[t] = s3; __syncthreads();
    for (int o = 128; o; o >>= 1) { if (t < o) red[t] += red[t + o]; __syncthreads(); }
    if (t == 0) res[2] = red[0];
    __syncthreads();

    if (t == 0) {
        dout[40] = sqrtf(racc[0]);
        dout[41] = sqrtf(racc[1]);
        dout[42] = res[0];
        dout[43] = f1b[0] * f1b[0];
        dout[44] = res[1];
        dout[45] = f2b[0] * f2b[0];
        dout[46] = res[2];
        dout[47] = f3b[0] * f3b[0];
    }
}

// ---------------- host ----------------

extern "C" void kernel_launch(void* const* d_in, const int* in_sizes, int n_in,
                              void* d_out, int out_size, void* d_ws, size_t ws_size,
                              hipStream_t stream) {
    const float* x    = (const float*)d_in[0];
    const float* Lr   = (const float*)d_in[5];
    const int*   sccs = (const int*)d_in[6];
    const float* W1   = (const float*)d_in[7];
    const float* b1   = (const float*)d_in[8];
    const float* W2   = (const float*)d_in[9];
    const float* b2   = (const float*)d_in[10];
    const float* Wr   = (const float*)d_in[11];
    const float* br   = (const float*)d_in[12];
    const float* f1w  = (const float*)d_in[13];
    const float* f1b  = (const float*)d_in[14];
    const float* f2w  = (const float*)d_in[15];
    const float* f2b  = (const float*)d_in[16];
    const float* f3w  = (const float*)d_in[17];
    const float* f3b  = (const float*)d_in[18];
    float* dout = (float*)d_out;

    char* ws = (char*)d_ws;
    size_t off = 0;
    auto alloc = [&](size_t bytes) -> char* {
        char* p = ws + off;
        off = (off + bytes + 255) & ~(size_t)255;
        return p;
    };
    float* outF = (float*)alloc((size_t)N4 * CC * 4);             // graph1 out, then reused as out2
    unsigned short* Cpb = (unsigned short*)alloc((size_t)6 * N4 * CC * 2);  // bf16 split-K partials
    unsigned short* Sb  = (unsigned short*)alloc((size_t)N4 * N4 * 2);      // bf16 distances
    unsigned short* Tall = (unsigned short*)alloc((size_t)N4 * KP6 * 2);
    unsigned short* W2T6 = Sb;   // alias: Sb dead after topk2
    float* xhat = (float*)alloc((size_t)N4 * 18 * 4);
    float* sq1  = (float*)alloc(N4 * 4);
    float* sq2  = (float*)alloc(N4 * 4);
    float* rs1  = (float*)alloc(N4 * 4);
    float* rs2  = (float*)alloc(N4 * 4);
    float* wv1  = (float*)alloc((size_t)N4 * KNN * 4);
    float* wv2  = (float*)alloc((size_t)N4 * KNN * 4);
    int*   ix1  = (int*)alloc((size_t)N4 * KNN * 4);
    int*   ix2  = (int*)alloc((size_t)N4 * KNN * 4);
    float* t2x  = (float*)alloc((size_t)N4 * FDIM * 4);
    float* tr1  = (float*)alloc((size_t)NRB * CC * 4);
    float* tr2  = (float*)alloc((size_t)NRB * CC * 4);
    char*  zbase = ws + off;
    float* Mb   = (float*)alloc(6 * CC * 4);
    float* Mb2  = (float*)alloc(6 * CC * 4);
    float* rbm  = (float*)alloc(CC * 4);
    float* otm  = (float*)alloc(CC * 4);
    float* h1p  = (float*)alloc(512 * 4);
    float* racc = (float*)alloc(64 * 4);
    float* rpre = (float*)alloc((size_t)NRB * CC * 4);
    float* vfr  = (float*)alloc((size_t)NRB * CC * 4);
    size_t zlen = (size_t)((ws + off) - zbase);
    if (off > ws_size) return;

    hipMemsetAsync(zbase, 0, zlen, stream);

    // ---- graph 1 (on x): fused distance + top-40 ----
    sqx_kernel<<<(N4 + 255) / 256, 256, 0, stream>>>(x, sq1, xhat);
    topk_fused1<<<N4, 512, 0, stream>>>(x, sq1, ix1, wv1, rs1);
    wnorm_kernel<<<(N4 * KNN + 255) / 256, 256, 0, stream>>>(wv1, ix1, rs1);

    // ---- cheb conv 1 (fused: fp32 out + bf16 Tall slice 0 + sq2 rowsums) ----
    spmv_cheb<<<(N4 + SNPB - 1) / SNPB, 256, 0, stream>>>(xhat, xhat, xhat + 6, ix1, wv1, 18, 18, 18, 1.f, 0.f);
    spmv_cheb<<<(N4 + SNPB - 1) / SNPB, 256, 0, stream>>>(xhat + 6, xhat, xhat + 12, ix1, wv1, 18, 18, 18, 2.f, 1.f);
    cheb1_out_kernel<<<N4 / 16, 256, 0, stream>>>(xhat, W1, b1, outF, Tall, sq2);

    matT6_partial<<<dim3(4, 32), 256, 0, stream>>>(outF, xhat + 6, 18, Mb);
    fro_kernel<<<24, 256, 0, stream>>>(Mb, racc + 0);

    vfr_kernel<<<dim3(4, NRB, 5), 256, 0, stream>>>(outF, sccs, vfr);

    // ---- graph 2 (on outF) ----
    gram2_mfma<<<dim3(N4 / 128, N4 / 256), 256, 0, stream>>>(Tall, sq2, Sb);
    topk_radix<<<N4, 512, 0, stream>>>(Sb, ix2, wv2, rs2);
    wnorm_kernel<<<(N4 * KNN + 255) / 256, 256, 0, stream>>>(wv2, ix2, rs2);

    // Sb dead -> build W2T6 in its space
    w2t_kernel<<<dim3(16, 16, 6), 256, 0, stream>>>(W2, W2T6);

    spmv_cheb<<<(N4 + SNPB - 1) / SNPB, 256, 0, stream>>>(x, x, t2x, ix2, wv2, FDIM, FDIM, FDIM, 1.f, 0.f);

    // ---- cheb recursion (bf16, into Tall slices 1..5; col-split for L2 residency) ----
    spmv_cheb_bf<<<dim3(N4, 2), 256, 0, stream>>>(Tall + 0 * KP, Tall + 0 * KP, Tall + 1 * KP, ix2, wv2, 1.f, 0.f);
    spmv_cheb_bf<<<dim3(N4, 2), 256, 0, stream>>>(Tall + 1 * KP, Tall + 0 * KP, Tall + 2 * KP, ix2, wv2, 2.f, 1.f);
    spmv_cheb_bf<<<dim3(N4, 2), 256, 0, stream>>>(Tall + 2 * KP, Tall + 1 * KP, Tall + 3 * KP, ix2, wv2, 2.f, 1.f);
    spmv_cheb_bf<<<dim3(N4, 2), 256, 0, stream>>>(Tall + 3 * KP, Tall + 2 * KP, Tall + 4 * KP, ix2, wv2, 2.f, 1.f);
    spmv_cheb_bf<<<dim3(N4, 2), 256, 0, stream>>>(Tall + 4 * KP, Tall + 3 * KP, Tall + 5 * KP, ix2, wv2, 2.f, 1.f);

    // ---- batched K=6144 GEMM (split-K=3, BK=64, bf16 partials, 128-tiles) ----
    gemm_mfma_big<<<dim3(N4 / 128, 8, 3), 256, 0, stream>>>(Tall, W2T6, Cpb);
    bias_relu_merge<<<(int)(((size_t)N4 * CC / 8 + 255) / 256), 256, 0, stream>>>(Cpb, b2, outF);

    // matT6 + colmax fused: one pass over out2
    matT6_colmax<<<dim3(4, 32), 256, 0, stream>>>(outF, t2x, FDIM, Mb2, otm);
    fro_kernel<<<24, 256, 0, stream>>>(Mb2, racc + 1);

    // ---- reeb cheb conv (K=3) ----
    reeb_mm_kernel<<<dim3(4, NRB), 256, 0, stream>>>(Lr, vfr, nullptr, tr1, 1.f);
    reeb_mm_kernel<<<dim3(4, NRB), 256, 0, stream>>>(Lr, tr1, vfr, tr2, 2.f);
    reeb_conv_splitk<<<dim3(4, 120), 256, 0, stream>>>(vfr, tr1, tr2, Wr, rpre);
    reeb_max_kernel<<<4, 256, 0, stream>>>(rpre, br, rbm);

    // ---- FC head ----
    fc1_kernel<<<dim3(2, 8), 256, 0, stream>>>(rbm, otm, f1w, h1p);
    fc23_kernel<<<1, 512, 0, stream>>>(h1p, f1b, f2w, f2b, f3w, f3b, dout);
    finalize_kernel<<<1, 256, 0, stream>>>(racc, f1w, f1b, f2w, f2b, f3w, f3b, dout);
}

// Round 18
// 569.820 us; speedup vs baseline: 1.0442x; 1.0442x over previous
//
#include <hip/hip_runtime.h>
#include <math.h>

#define N4    4096
#define FDIM  6
#define CC    1000
#define KP    1024
#define KP6   (6 * KP)
#define KNN   40
#define NRB   20
#define SSC   205

typedef __attribute__((ext_vector_type(8))) short bf16x8;
typedef __attribute__((ext_vector_type(4))) float f32x4;

__device__ __forceinline__ unsigned short f2bf(float f) {
    unsigned u = __float_as_uint(f);
    u = (u + 0x7fffu + ((u >> 16) & 1u)) >> 16;
    return (unsigned short)u;
}
__device__ __forceinline__ float bf2f(short s) {
    return __uint_as_float(((unsigned)(unsigned short)s) << 16);
}

// distance -> descending-sortable key (smaller d == larger key)
__device__ __forceinline__ unsigned d2key(float d) {
    unsigned u = __float_as_uint(d);
    return ((int)u < 0) ? u : (~u) ^ 0x80000000u;
}
__device__ __forceinline__ float key2d(unsigned k) {
    unsigned u = (k >> 31) ? k : (~k) ^ 0x80000000u;
    return __uint_as_float(u);
}

// async global->LDS, 16B per lane; LDS dest is wave-uniform base + lane*16
__device__ __forceinline__ void gload16(const unsigned short* g, short* l) {
    __builtin_amdgcn_global_load_lds(
        (const __attribute__((address_space(1))) unsigned int*)g,
        (__attribute__((address_space(3))) unsigned int*)l, 16, 0, 0);
}

// ---------------- graph build ----------------

__global__ __launch_bounds__(256) void sqx_kernel(const float* __restrict__ x,
                                                  float* __restrict__ sq1,
                                                  float* __restrict__ xhat) {
    int n = blockIdx.x * blockDim.x + threadIdx.x;
    if (n >= N4) return;
    float s = 0.f;
#pragma unroll
    for (int f = 0; f < FDIM; ++f) {
        float v = x[n * FDIM + f];
        s += v * v;
        xhat[n * 18 + f] = v;
    }
    sq1[n] = s;
}

// ---------------- radix top-40 on distance keys (exact) ----------------

#define NHC 4
#define HSTRIDE 257

struct TopkSh {
    unsigned sv[N4];                 // 16 KB keys
    int hist[NHC * HSTRIDE];         // 4.1 KB (4 copies: RL-flushed atomics are rare)
    int sc[256];                     // hist_pick scratch + equals strip counts
    float red[8];
    unsigned short cidx[N4];         // compacted indices
    unsigned short cv16[N4];         // compacted top-16 key bits (single-load scans)
    unsigned s_pfx;
    int s_need, s_cnt, s_m;
};

// zero scalars + histogram copies; call BEFORE key generation (which histograms inline)
__device__ __forceinline__ void topk_prep(TopkSh& sh, int t) {
    if (t == 0) { sh.s_pfx = 0u; sh.s_need = KNN; sh.s_cnt = 0; sh.s_m = 0; }
    for (int q = t; q < NHC * HSTRIDE; q += 512) sh.hist[q] = 0;
}

__device__ __forceinline__ void hist_pick(TopkSh& sh, int level, int t, int lane, int w, int nc) {
    if (t < 256) {
        int cnt = 0;
        for (int c = 0; c < nc; ++c) cnt += sh.hist[c * HSTRIDE + t];
        sh.sc[t] = cnt;
    }
    __syncthreads();
    if (w == 0) {
        int need = sh.s_need;
        unsigned pfx = sh.s_pfx;
        int c0 = sh.sc[4 * lane + 0], c1 = sh.sc[4 * lane + 1];
        int c2 = sh.sc[4 * lane + 2], c3 = sh.sc[4 * lane + 3];
        int s = c0 + c1 + c2 + c3;
        int suf = s;
#pragma unroll
        for (int off = 1; off < 64; off <<= 1) {
            int ov = __shfl_down(suf, off, 64);
            if (lane + off < 64) suf += ov;
        }
        int above = suf - s;
        int i3 = above + c3, i2 = i3 + c2, i1 = i2 + c1, i0 = i1 + c0;
        if (i3 >= need && i3 - c3 < need) { sh.s_need = need - (i3 - c3); sh.s_pfx = pfx | ((unsigned)(4 * lane + 3) << level); }
        if (i2 >= need && i2 - c2 < need) { sh.s_need = need - (i2 - c2); sh.s_pfx = pfx | ((unsigned)(4 * lane + 2) << level); }
        if (i1 >= need && i1 - c1 < need) { sh.s_need = need - (i1 - c1); sh.s_pfx = pfx | ((unsigned)(4 * lane + 1) << level); }
        if (i0 >= need && i0 - c0 < need) { sh.s_need = need - (i0 - c0); sh.s_pfx = pfx | ((unsigned)(4 * lane + 0) << level); }
    }
    __syncthreads();
}

// entry state: sv[] written, pass-1 (top byte) histograms accumulated by the caller.
// LASTLEVEL=0: full 32-bit refinement. LASTLEVEL=16: keys have constant low-16
// within a 16-bit prefix (bf16-derived): low16 = bit31 ? 0x0000 : 0xFFFF.
template<int LASTLEVEL>
__device__ void topk_core(TopkSh& sh, int n, int* __restrict__ idx,
                          float* __restrict__ val, float* __restrict__ rowsum) {
    int t = threadIdx.x, lane = t & 63, w = t >> 6;
    __syncthreads();
    hist_pick(sh, 24, t, lane, w, NHC);
    unsigned b1 = sh.s_pfx >> 24;

    // compact ALL tb >= b1 into cidx + cv16 (single ballot)
    for (int i = t; i < N4; i += 512) {
        unsigned u = sh.sv[i];
        bool isc = ((u >> 24) >= b1);
        unsigned long long mm = __ballot(isc);
        int cw = __popcll(mm);
        int base = 0;
        if (lane == 0 && cw) base = atomicAdd(&sh.s_m, cw);
        base = __shfl(base, 0);
        if (isc) {
            int p = base + __popcll(mm & ((1ull << lane) - 1ull));
            sh.cidx[p] = (unsigned short)i;
            sh.cv16[p] = (unsigned short)(u >> 16);
        }
    }
    __syncthreads();
    int mcnt = sh.s_m;

    // level 16: single-load scan over cv16
    for (int q = t; q < HSTRIDE; q += 512) sh.hist[q] = 0;
    __syncthreads();
    {
        unsigned pb = sh.s_pfx >> 24;
        for (int j = t; j < mcnt; j += 512) {
            unsigned v = sh.cv16[j];
            if ((v >> 8) == pb) atomicAdd(&sh.hist[v & 255], 1);
        }
    }
    __syncthreads();
    hist_pick(sh, 16, t, lane, w, 1);

    if (LASTLEVEL == 0) {
        // level 8: cv16 prefilter, dependent sv load only on 16-bit prefix match
        for (int q = t; q < HSTRIDE; q += 512) sh.hist[q] = 0;
        __syncthreads();
        {
            unsigned short p16 = (unsigned short)(sh.s_pfx >> 16);
            for (int j = t; j < mcnt; j += 512) {
                if (sh.cv16[j] == p16) {
                    unsigned u = sh.sv[sh.cidx[j]];
                    atomicAdd(&sh.hist[(u >> 8) & 255], 1);
                }
            }
        }
        __syncthreads();
        hist_pick(sh, 8, t, lane, w, 1);

        // level 0
        for (int q = t; q < HSTRIDE; q += 512) sh.hist[q] = 0;
        __syncthreads();
        {
            unsigned pfx = sh.s_pfx;
            unsigned short p16 = (unsigned short)(pfx >> 16);
            for (int j = t; j < mcnt; j += 512) {
                if (sh.cv16[j] == p16) {
                    unsigned u = sh.sv[sh.cidx[j]];
                    if ((u >> 8) == (pfx >> 8)) atomicAdd(&sh.hist[u & 255], 1);
                }
            }
        }
        __syncthreads();
        hist_pick(sh, 0, t, lane, w, 1);
    }

    unsigned Tbits = sh.s_pfx;
    if (LASTLEVEL == 16) Tbits |= (Tbits & 0x80000000u) ? 0u : 0xFFFFu;
    float Tf = __expf(-key2d(Tbits));
    int needEq = sh.s_need;

    // collect >T (cv16 prefilter; LASTLEVEL=16 reconstructs the full key from cv16)
    float psum = 0.f;
    unsigned short T16 = (unsigned short)(Tbits >> 16);
    for (int j = t; j < mcnt; j += 512) {
        unsigned short v = sh.cv16[j];
        if (v >= T16) {
            unsigned u;
            if (LASTLEVEL == 16)
                u = ((unsigned)v << 16) | ((v & 0x8000u) ? 0u : 0xFFFFu);
            else
                u = sh.sv[sh.cidx[j]];
            if (u > Tbits) {
                int p = atomicAdd(&sh.s_cnt, 1);
                float fv = __expf(-key2d(u));
                idx[(size_t)n * KNN + p] = (int)sh.cidx[j];
                val[(size_t)n * KNN + p] = fv;
                psum += fv;
            }
        }
    }
    // wave-level reduce, then 8 partials
#pragma unroll
    for (int o = 32; o; o >>= 1) psum += __shfl_down(psum, o);
    if (lane == 0) sh.red[w] = psum;
    __syncthreads();
    if (t == 0) {
        float s = 0.f;
#pragma unroll
        for (int q = 0; q < 8; ++q) s += sh.red[q];
        rowsum[n] = s + (float)needEq * Tf;
    }

    // equals: earliest indices first, strip-parallel across the 8 waves
    {
        int filled0 = KNN - needEq;
        int base_i = w * 512;
        int cnt = 0;
#pragma unroll
        for (int q = 0; q < 8; ++q) {
            bool eq = (sh.sv[base_i + q * 64 + lane] == Tbits);
            cnt += __popcll(__ballot(eq));
        }
        if (lane == 0) sh.sc[w] = cnt;
        __syncthreads();
        int pre = 0;
        for (int q = 0; q < w; ++q) pre += sh.sc[q];
        if (pre < needEq) {
            int run = pre;
            for (int q = 0; q < 8 && run < needEq; ++q) {
                bool eq = (sh.sv[base_i + q * 64 + lane] == Tbits);
                unsigned long long m = __ballot(eq);
                int lpre = __popcll(m & ((1ull << lane) - 1ull));
                if (eq && run + lpre < needEq) {
                    idx[(size_t)n * KNN + filled0 + run + lpre] = base_i + q * 64 + lane;
                    val[(size_t)n * KNN + filled0 + run + lpre] = Tf;
                }
                run += __popcll(m);
            }
        }
    }
}

__global__ __launch_bounds__(512) void topk_fused1(const float* __restrict__ x,
                                                   const float* __restrict__ sq1,
                                                   int* __restrict__ idx, float* __restrict__ val,
                                                   float* __restrict__ rowsum) {
    __shared__ TopkSh sh;
    __shared__ float xn[FDIM];
    __shared__ float sns;
    int n = blockIdx.x;
    int t = threadIdx.x;
    if (t < FDIM) xn[t] = x[n * FDIM + t];
    if (t == FDIM) sns = sq1[n];
    topk_prep(sh, t);
    __syncthreads();
    float x0 = xn[0], x1 = xn[1], x2 = xn[2], x3 = xn[3], x4 = xn[4], x5 = xn[5];
    float sn = sns;
    int* hw = &sh.hist[(t & 3) * HSTRIDE];
    unsigned prevb = 0xFFFFFFFFu; int rl = 0;
    for (int i = t; i < N4; i += 512) {
        const float2* xi = (const float2*)(x + i * FDIM);
        float2 p0 = xi[0], p1 = xi[1], p2 = xi[2];
        float d = x0 * p0.x + x1 * p0.y + x2 * p1.x + x3 * p1.y + x4 * p2.x + x5 * p2.y;
        float e = sn + sq1[i] - 2.f * d;
        unsigned k = d2key(e);
        sh.sv[i] = k;
        unsigned b = k >> 24;
        if (b == prevb) ++rl;
        else { if (rl) atomicAdd(&hw[prevb], rl); prevb = b; rl = 1; }
    }
    if (rl) atomicAdd(&hw[prevb], rl);
    topk_core<0>(sh, n, idx, val, rowsum);
}

// graph-2: reads precomputed bf16 distance row; keys are 16-bit-exact
__global__ __launch_bounds__(512) void topk_radix(const unsigned short* __restrict__ S,
                                                  int* __restrict__ idx, float* __restrict__ val,
                                                  float* __restrict__ rowsum) {
    __shared__ TopkSh sh;
    int n = blockIdx.x;
    int t = threadIdx.x;
    topk_prep(sh, t);
    const unsigned short* row = S + (size_t)n * N4;
    bf16x8 a = *(const bf16x8*)(row + 8 * t);
    __syncthreads();
    int* hw = &sh.hist[(t & 3) * HSTRIDE];
    unsigned prevb = 0xFFFFFFFFu; int rl = 0;
#pragma unroll
    for (int q = 0; q < 8; ++q) {
        unsigned k = d2key(bf2f(a[q]));
        sh.sv[8 * t + q] = k;
        unsigned b = k >> 24;
        if (b == prevb) ++rl;
        else { if (rl) atomicAdd(&hw[prevb], rl); prevb = b; rl = 1; }
    }
    if (rl) atomicAdd(&hw[prevb], rl);
    topk_core<16>(sh, n, idx, val, rowsum);
}

// wnorm with inline rsqrt; rs = row sums
__global__ __launch_bounds__(256) void wnorm_kernel(float* __restrict__ wv,
                                                    const int* __restrict__ idx,
                                                    const float* __restrict__ rs) {
    int i = blockIdx.x * 256 + threadIdx.x;
    if (i >= N4 * KNN) return;
    int n = i / KNN;
    wv[i] = wv[i] * rsqrtf(rs[n]) * rsqrtf(rs[idx[i]]);
}

// Tn[n,:] = a*(Tc[n,:] - sum_j wv[n,j]*Tc[idx[n,j],:]) - b*Tp[n,:]   (F small, fp32)
// one block per node, 64 threads: gather-latency-bound -> many small blocks = max TLP
// (round-17 dense remap to 98 blocks regressed 20 us: idle lanes are free, idle CUs are not)
__global__ __launch_bounds__(64) void spmv_cheb(const float* __restrict__ Tc,
                                                const float* __restrict__ Tp,
                                                float* __restrict__ Tn,
                                                const int* __restrict__ idx,
                                                const float* __restrict__ wv,
                                                int F, int sC, int sP, int sN,
                                                float a, float b) {
    __shared__ int   si[KNN];
    __shared__ float sw[KNN];
    int n = blockIdx.x;
    if (threadIdx.x < KNN) {
        si[threadIdx.x] = idx[(size_t)n * KNN + threadIdx.x];
        sw[threadIdx.x] = wv[(size_t)n * KNN + threadIdx.x];
    }
    __syncthreads();
    for (int c = threadIdx.x; c < F; c += blockDim.x) {
        float s = 0.f;
#pragma unroll 8
        for (int j = 0; j < KNN; ++j) s += sw[j] * Tc[(size_t)si[j] * sC + c];
        float v = a * (Tc[(size_t)n * sC + c] - s);
        if (b != 0.f) v -= b * Tp[(size_t)n * sP + c];
        Tn[(size_t)n * sN + c] = v;
    }
}

// bf16-resident recursion over Tall slices (row stride KP6).
// grid (N4, 2): blockIdx.y = column half (slow dispatch dim) -> per-phase gather
// working set 4 MB -> fits per-XCD L2 (8 MB slice did not).
__global__ __launch_bounds__(256) void spmv_cheb_bf(const unsigned short* __restrict__ Tcbf,
                                                    const unsigned short* __restrict__ Tpbf,
                                                    unsigned short* __restrict__ Tnbf,
                                                    const int* __restrict__ idx,
                                                    const float* __restrict__ wv,
                                                    float a, float b) {
    __shared__ int   si[KNN];
    __shared__ float sw[KNN];
    __shared__ float part[3][64][9];   // +1 pad breaks write-bank aliasing
    int n = blockIdx.x;
    int t = threadIdx.x;
    int tt = t & 63, g = t >> 6;       // 64 col-groups x 4 neighbor-groups of 10
    if (t < KNN) {
        si[t] = idx[(size_t)n * KNN + t];
        sw[t] = wv[(size_t)n * KNN + t];
    }
    __syncthreads();
    int c = blockIdx.y * 512 + tt * 8;
    float acc0 = 0, acc1 = 0, acc2 = 0, acc3 = 0, acc4 = 0, acc5 = 0, acc6 = 0, acc7 = 0;
    int j0 = g * 10;
#pragma unroll
    for (int j = j0; j < j0 + 10; ++j) {
        bf16x8 v = *(const bf16x8*)(Tcbf + (size_t)si[j] * KP6 + c);
        float wj = sw[j];
        acc0 += wj * bf2f(v[0]); acc1 += wj * bf2f(v[1]);
        acc2 += wj * bf2f(v[2]); acc3 += wj * bf2f(v[3]);
        acc4 += wj * bf2f(v[4]); acc5 += wj * bf2f(v[5]);
        acc6 += wj * bf2f(v[6]); acc7 += wj * bf2f(v[7]);
    }
    if (g) {
        float* p = part[g - 1][tt];
        p[0] = acc0; p[1] = acc1; p[2] = acc2; p[3] = acc3;
        p[4] = acc4; p[5] = acc5; p[6] = acc6; p[7] = acc7;
    }
    __syncthreads();
    if (g == 0) {
#pragma unroll
        for (int pg = 0; pg < 3; ++pg) {
            const float* p = part[pg][tt];
            acc0 += p[0]; acc1 += p[1]; acc2 += p[2]; acc3 += p[3];
            acc4 += p[4]; acc5 += p[5]; acc6 += p[6]; acc7 += p[7];
        }
        bf16x8 tc = *(const bf16x8*)(Tcbf + (size_t)n * KP6 + c);
        float o0 = a * (bf2f(tc[0]) - acc0), o1 = a * (bf2f(tc[1]) - acc1);
        float o2 = a * (bf2f(tc[2]) - acc2), o3 = a * (bf2f(tc[3]) - acc3);
        float o4 = a * (bf2f(tc[4]) - acc4), o5 = a * (bf2f(tc[5]) - acc5);
        float o6 = a * (bf2f(tc[6]) - acc6), o7 = a * (bf2f(tc[7]) - acc7);
        if (b != 0.f) {
            bf16x8 tp = *(const bf16x8*)(Tpbf + (size_t)n * KP6 + c);
            o0 -= b * bf2f(tp[0]); o1 -= b * bf2f(tp[1]);
            o2 -= b * bf2f(tp[2]); o3 -= b * bf2f(tp[3]);
            o4 -= b * bf2f(tp[4]); o5 -= b * bf2f(tp[5]);
            o6 -= b * bf2f(tp[6]); o7 -= b * bf2f(tp[7]);
        }
        bf16x8 ob;
        ob[0] = (short)f2bf(o0); ob[1] = (short)f2bf(o1);
        ob[2] = (short)f2bf(o2); ob[3] = (short)f2bf(o3);
        ob[4] = (short)f2bf(o4); ob[5] = (short)f2bf(o5);
        ob[6] = (short)f2bf(o6); ob[7] = (short)f2bf(o7);
        *(bf16x8*)(Tnbf + (size_t)n * KP6 + c) = ob;
    }
}

// W2 [6*CC x CC] fp32 -> W2T6 [1024 rows(n)][KP6 cols(k)] bf16; vectorized bf16x8 stores
__global__ __launch_bounds__(256) void w2t_kernel(const float* __restrict__ W2,
                                                  unsigned short* __restrict__ out) {
    __shared__ unsigned short tile[64][65];
    int t = threadIdx.x;
    int k0 = blockIdx.x * 64, n0 = blockIdx.y * 64, s = blockIdx.z;
#pragma unroll
    for (int p = 0; p < 16; ++p) {
        int i = p * 256 + t;
        int kk = i >> 6, nn = i & 63;
        int k = k0 + kk, n = n0 + nn;
        float v = (k < CC && n < CC) ? W2[((size_t)s * CC + k) * CC + n] : 0.f;
        tile[kk][nn] = f2bf(v);
    }
    __syncthreads();
#pragma unroll
    for (int p = 0; p < 2; ++p) {
        int i = p * 256 + t;          // 512 chunks: 64 rows(nn) x 8 k-chunks
        int nn = i >> 3, kk = (i & 7) * 8;
        bf16x8 v;
#pragma unroll
        for (int j = 0; j < 8; ++j) v[j] = (short)tile[kk + j][nn];
        *(bf16x8*)(out + (size_t)(n0 + nn) * KP6 + (size_t)s * KP + k0 + kk) = v;
    }
}

// ---------------- MFMA GEMM cores ----------------

#define LDT 32                      // linear LDS tile pitch (shorts)
#define SP2 136                     // 128-tile epilogue staging pitch
#define SP 264                      // 256-tile epilogue staging pitch
#define ABUF (128 * LDT)            // one [128][32] tile (shorts)
#define BBUF (256 * LDT)            // one [256][32] tile (shorts)

// 128x128-tile core, BK=64: two linear [128][32] k-half tiles per matrix,
// single-buffer, 2 barriers per BK64 step (measured good: round 8, 62 us).
template<int STR>
__device__ __forceinline__ void gemm_core128_bk64(const unsigned short* __restrict__ Ag,
                                                  const unsigned short* __restrict__ Bg,
                                                  short* sm, int t,
                                                  int kbeg, int kend,
                                                  f32x4 (&acc)[4][4]) {
    int l = t & 63, w = t >> 6;
    int wm = (w >> 1) * 64, wn = (w & 1) * 64;
    int lr = l & 15, lq8 = (l >> 4) * 8;
    short* A0 = sm;
    short* A1 = sm + ABUF;
    short* B0 = sm + 2 * ABUF;
    short* B1 = sm + 3 * ABUF;
    // staging: one gload16 covers 16 rows x 32 cols; lane l -> row +(l>>2), col (l&3)*8
    // LDS lands linear: (l>>2)*32 + (l&3)*8 == 8*l
    size_t ga0 = (size_t)(32 * w + (l >> 2)) * STR + (l & 3) * 8;
    size_t ga1 = ga0 + (size_t)16 * STR;
    int lo = (32 * w) * LDT;
    for (int k0 = kbeg; k0 < kend; k0 += 64) {
        gload16(Ag + ga0 + k0,      A0 + lo);
        gload16(Ag + ga1 + k0,      A0 + lo + 16 * LDT);
        gload16(Ag + ga0 + k0 + 32, A1 + lo);
        gload16(Ag + ga1 + k0 + 32, A1 + lo + 16 * LDT);
        gload16(Bg + ga0 + k0,      B0 + lo);
        gload16(Bg + ga1 + k0,      B0 + lo + 16 * LDT);
        gload16(Bg + ga0 + k0 + 32, B1 + lo);
        gload16(Bg + ga1 + k0 + 32, B1 + lo + 16 * LDT);
        __syncthreads();
        bf16x8 af[4], bfr[4];
#pragma unroll
        for (int mi = 0; mi < 4; ++mi)
            af[mi] = *(const bf16x8*)&A0[(wm + mi * 16 + lr) * LDT + lq8];
#pragma unroll
        for (int ni = 0; ni < 4; ++ni)
            bfr[ni] = *(const bf16x8*)&B0[(wn + ni * 16 + lr) * LDT + lq8];
#pragma unroll
        for (int mi = 0; mi < 4; ++mi)
#pragma unroll
            for (int ni = 0; ni < 4; ++ni)
                acc[mi][ni] = __builtin_amdgcn_mfma_f32_16x16x32_bf16(af[mi], bfr[ni], acc[mi][ni], 0, 0, 0);
#pragma unroll
        for (int mi = 0; mi < 4; ++mi)
            af[mi] = *(const bf16x8*)&A1[(wm + mi * 16 + lr) * LDT + lq8];
#pragma unroll
        for (int ni = 0; ni < 4; ++ni)
            bfr[ni] = *(const bf16x8*)&B1[(wn + ni * 16 + lr) * LDT + lq8];
#pragma unroll
        for (int mi = 0; mi < 4; ++mi)
#pragma unroll
            for (int ni = 0; ni < 4; ++ni)
                acc[mi][ni] = __builtin_amdgcn_mfma_f32_16x16x32_bf16(af[mi], bfr[ni], acc[mi][ni], 0, 0, 0);
        __syncthreads();
    }
}

// batched cheb2 GEMM: bf16 partials, 128x128 tiles, BK=64, split-K=3
// grid (32 m, 8 n, 3 z) -- measured-good round-8 config (62 us)
__global__ __launch_bounds__(256) void gemm_mfma_big(const unsigned short* __restrict__ A,
                                                     const unsigned short* __restrict__ B,
                                                     unsigned short* __restrict__ Cp) {
    __shared__ short smem[4 * ABUF];   // A0,A1,B0,B1 = 32 KB
    int t = threadIdx.x;
    int m0 = blockIdx.x * 128, n0 = blockIdx.y * 128;
    int kz = blockIdx.z;
    unsigned short* C = Cp + (size_t)kz * N4 * CC;
    f32x4 acc[4][4] = {};
    gemm_core128_bk64<KP6>(A + (size_t)m0 * KP6, B + (size_t)n0 * KP6, smem, t,
                           kz * 2 * KP, kz * 2 * KP + 2 * KP, acc);
    int l = t & 63, w = t >> 6;
    int wn = (w & 1) * 64;
    int lr = l & 15, lq4 = (l >> 4) * 4;
    int lrow = (w >> 1) * 16 + lq4;
#pragma unroll
    for (int mi = 0; mi < 4; ++mi) {
        __syncthreads();
#pragma unroll
        for (int ni = 0; ni < 4; ++ni) {
            int col = wn + ni * 16 + lr;
            f32x4 v = acc[mi][ni];
#pragma unroll
            for (int r = 0; r < 4; ++r) smem[(lrow + r) * SP2 + col] = (short)f2bf(v[r]);
        }
        __syncthreads();
#pragma unroll
        for (int q = 0; q < 2; ++q) {
            int row = q * 16 + (t >> 4);
            int col = (t & 15) * 8;
            int gm = m0 + (row >> 4) * 64 + mi * 16 + (row & 15);
            int gn = n0 + col;
            if (gn < CC) {
                bf16x8 vv = *(bf16x8*)&smem[row * SP2 + col];
                *(bf16x8*)(C + (size_t)gm * CC + gn) = vv;
            }
        }
    }
}

// out2 = relu(sum_z bf16 Cz + b2) -> fp32 out  (3 split-K slices)
__global__ __launch_bounds__(256) void bias_relu_merge(const unsigned short* __restrict__ Cp,
                                                       const float* __restrict__ b2,
                                                       float* __restrict__ out2) {
    size_t i8 = (size_t)blockIdx.x * 256 + threadIdx.x;
    if (i8 >= (size_t)N4 * CC / 8) return;
    size_t i = i8 * 8;
    int c = (int)(i % CC);
    const size_t S = (size_t)N4 * CC;
    float s[8] = {};
#pragma unroll
    for (int z = 0; z < 3; ++z) {
        bf16x8 v = *(const bf16x8*)(Cp + z * S + i);
#pragma unroll
        for (int q = 0; q < 8; ++q) s[q] += bf2f(v[q]);
    }
    float4 o0, o1;
    o0.x = fmaxf(s[0] + b2[c + 0], 0.f); o0.y = fmaxf(s[1] + b2[c + 1], 0.f);
    o0.z = fmaxf(s[2] + b2[c + 2], 0.f); o0.w = fmaxf(s[3] + b2[c + 3], 0.f);
    o1.x = fmaxf(s[4] + b2[c + 4], 0.f); o1.y = fmaxf(s[5] + b2[c + 5], 0.f);
    o1.z = fmaxf(s[6] + b2[c + 6], 0.f); o1.w = fmaxf(s[7] + b2[c + 7], 0.f);
    *(float4*)(out2 + i) = o0;
    *(float4*)(out2 + i + 4) = o1;
}

// gram over Tall slice 0 -> bf16 distances, 128x256 tiles, BK=64 single-buffer
__global__ __launch_bounds__(256, 2) void gram2_mfma(const unsigned short* __restrict__ Tall,
                                                     const float* __restrict__ sq2,
                                                     unsigned short* __restrict__ S) {
    __shared__ short smem[2 * ABUF + 2 * BBUF];   // A0,A1,B0,B1 = 48 KB
    int t = threadIdx.x;
    int m0 = blockIdx.x * 128, n0 = blockIdx.y * 256;
    int l = t & 63, w = t >> 6;
    int wm = (w >> 1) * 64, wn = (w & 1) * 128;
    int lr = l & 15, lq8 = (l >> 4) * 8;
    short* A0 = smem;
    short* A1 = smem + ABUF;
    short* B0 = smem + 2 * ABUF;
    short* B1 = smem + 2 * ABUF + BBUF;
    const unsigned short* Ag = Tall + (size_t)m0 * KP6;
    const unsigned short* Bg = Tall + (size_t)n0 * KP6;
    // A: wave w covers rows [32w,32w+32) via 2 issues; B: rows [64w,64w+64) via 4 issues
    size_t gaA = (size_t)(32 * w + (l >> 2)) * KP6 + (l & 3) * 8;
    size_t gaB = (size_t)(64 * w + (l >> 2)) * KP6 + (l & 3) * 8;
    int loA = (32 * w) * LDT;
    int loB = (64 * w) * LDT;
    f32x4 acc[4][8] = {};
    for (int k0 = 0; k0 < KP; k0 += 64) {
        gload16(Ag + gaA + k0,                         A0 + loA);
        gload16(Ag + gaA + (size_t)16 * KP6 + k0,      A0 + loA + 16 * LDT);
        gload16(Ag + gaA + k0 + 32,                    A1 + loA);
        gload16(Ag + gaA + (size_t)16 * KP6 + k0 + 32, A1 + loA + 16 * LDT);
#pragma unroll
        for (int r = 0; r < 4; ++r) {
            gload16(Bg + gaB + (size_t)(16 * r) * KP6 + k0,      B0 + loB + 16 * r * LDT);
            gload16(Bg + gaB + (size_t)(16 * r) * KP6 + k0 + 32, B1 + loB + 16 * r * LDT);
        }
        __syncthreads();
        bf16x8 af[4], bfr[8];
#pragma unroll
        for (int mi = 0; mi < 4; ++mi)
            af[mi] = *(const bf16x8*)&A0[(wm + mi * 16 + lr) * LDT + lq8];
#pragma unroll
        for (int ni = 0; ni < 8; ++ni)
            bfr[ni] = *(const bf16x8*)&B0[(wn + ni * 16 + lr) * LDT + lq8];
#pragma unroll
        for (int mi = 0; mi < 4; ++mi)
#pragma unroll
            for (int ni = 0; ni < 8; ++ni)
                acc[mi][ni] = __builtin_amdgcn_mfma_f32_16x16x32_bf16(af[mi], bfr[ni], acc[mi][ni], 0, 0, 0);
#pragma unroll
        for (int mi = 0; mi < 4; ++mi)
            af[mi] = *(const bf16x8*)&A1[(wm + mi * 16 + lr) * LDT + lq8];
#pragma unroll
        for (int ni = 0; ni < 8; ++ni)
            bfr[ni] = *(const bf16x8*)&B1[(wn + ni * 16 + lr) * LDT + lq8];
#pragma unroll
        for (int mi = 0; mi < 4; ++mi)
#pragma unroll
            for (int ni = 0; ni < 8; ++ni)
                acc[mi][ni] = __builtin_amdgcn_mfma_f32_16x16x32_bf16(af[mi], bfr[ni], acc[mi][ni], 0, 0, 0);
        __syncthreads();
    }
    int lq4 = (l >> 4) * 4;
    int lrow = (w >> 1) * 16 + lq4;
#pragma unroll
    for (int mi = 0; mi < 4; ++mi) {
        __syncthreads();
        int mbase = m0 + (w >> 1) * 64 + mi * 16 + lq4;
#pragma unroll
        for (int ni = 0; ni < 8; ++ni) {
            int col = wn + ni * 16 + lr;
            float sn = sq2[n0 + col];
            f32x4 v = acc[mi][ni];
#pragma unroll
            for (int r = 0; r < 4; ++r)
                smem[(lrow + r) * SP + col] = (short)f2bf(sq2[mbase + r] + sn - 2.f * v[r]);
        }
        __syncthreads();
#pragma unroll
        for (int q = 0; q < 4; ++q) {
            int row = q * 8 + (t >> 5);
            int col = (t & 31) * 8;
            int gm = m0 + (row >> 4) * 64 + mi * 16 + (row & 15);
            int gn = n0 + col;
            bf16x8 vv = *(bf16x8*)&smem[row * SP + col];
            *(bf16x8*)(S + (size_t)gm * N4 + gn) = vv;
        }
    }
}

// ---------------- cheb conv 1 (fused: outF fp32 + Tall slice-0 bf16 + sq2 rowsums) ----------------

__global__ __launch_bounds__(256) void cheb1_out_kernel(const float* __restrict__ xhat,
                                                        const float* __restrict__ W1,
                                                        const float* __restrict__ b1,
                                                        float* __restrict__ outF,
                                                        unsigned short* __restrict__ tall,
                                                        float* __restrict__ sq2) {
    __shared__ float xh[16][18];
    __shared__ float wred[4][16];
    int n0 = blockIdx.x * 16;
    int tid = threadIdx.x;
    for (int i = tid; i < 16 * 18; i += 256) xh[i / 18][i % 18] = xhat[(size_t)n0 * 18 + i];
    __syncthreads();
    float ps[16];
#pragma unroll
    for (int r = 0; r < 16; ++r) ps[r] = 0.f;
    for (int c0 = 0; c0 < KP; c0 += 256) {
        int c = c0 + tid;
        if (c < CC) {
            float acc[16];
#pragma unroll
            for (int r = 0; r < 16; ++r) acc[r] = 0.f;
            for (int f = 0; f < 18; ++f) {
                float wv = W1[(size_t)f * CC + c];
#pragma unroll
                for (int r = 0; r < 16; ++r) acc[r] += xh[r][f] * wv;
            }
            float bb = b1[c];
#pragma unroll
            for (int r = 0; r < 16; ++r) {
                float v = fmaxf(acc[r] + bb, 0.f);
                outF[(size_t)(n0 + r) * CC + c] = v;
                tall[(size_t)(n0 + r) * KP6 + c] = f2bf(v);
                ps[r] += v * v;
            }
        } else {   // zero-pad Tall cols [CC, KP)
#pragma unroll
            for (int r = 0; r < 16; ++r)
                tall[(size_t)(n0 + r) * KP6 + c] = 0;
        }
    }
    // reduce ps across 256 threads: per-wave shfl, then 4-way LDS combine
    int lane = tid & 63, w = tid >> 6;
#pragma unroll
    for (int r = 0; r < 16; ++r) {
        float s = ps[r];
#pragma unroll
        for (int o = 32; o; o >>= 1) s += __shfl_down(s, o);
        if (lane == 0) wred[w][r] = s;
    }
    __syncthreads();
    if (tid < 16)
        sq2[n0 + tid] = wred[0][tid] + wred[1][tid] + wred[2][tid] + wred[3][tid];
}

// ---------------- regs (frobenius of O^T @ T) ----------------
// 64-row n-chunks, grid (4, 64): 256 blocks (was 128 -> half the GPU idle)

__global__ __launch_bounds__(256) void matT6_partial(const float* __restrict__ O,
                                                     const float* __restrict__ T, int ts,
                                                     float* __restrict__ M) {
    __shared__ float sT[64][6];
    int t = threadIdx.x;
    int c = blockIdx.x * 256 + t;
    int n0 = blockIdx.y * 64;
    for (int i = t; i < 64 * 6; i += 256) {
        int nn = i / 6, f = i % 6;
        sT[nn][f] = T[(size_t)(n0 + nn) * ts + f];
    }
    __syncthreads();
    if (c >= CC) return;
    float a0 = 0, a1 = 0, a2 = 0, a3 = 0, a4 = 0, a5 = 0;
    for (int nn = 0; nn < 64; ++nn) {
        float o = O[(size_t)(n0 + nn) * CC + c];
        a0 += o * sT[nn][0]; a1 += o * sT[nn][1]; a2 += o * sT[nn][2];
        a3 += o * sT[nn][3]; a4 += o * sT[nn][4]; a5 += o * sT[nn][5];
    }
    atomicAdd(&M[0 * CC + c], a0);
    atomicAdd(&M[1 * CC + c], a1);
    atomicAdd(&M[2 * CC + c], a2);
    atomicAdd(&M[3 * CC + c], a3);
    atomicAdd(&M[4 * CC + c], a4);
    atomicAdd(&M[5 * CC + c], a5);
}

// matT6 + per-column max in one pass over O (used for the out2 pass; dst zeroed, O >= 0)
__global__ __launch_bounds__(256) void matT6_colmax(const float* __restrict__ O,
                                                    const float* __restrict__ T, int ts,
                                                    float* __restrict__ M,
                                                    float* __restrict__ dst) {
    __shared__ float sT[64][6];
    int t = threadIdx.x;
    int c = blockIdx.x * 256 + t;
    int n0 = blockIdx.y * 64;
    for (int i = t; i < 64 * 6; i += 256) {
        int nn = i / 6, f = i % 6;
        sT[nn][f] = T[(size_t)(n0 + nn) * ts + f];
    }
    __syncthreads();
    if (c >= CC) return;
    float a0 = 0, a1 = 0, a2 = 0, a3 = 0, a4 = 0, a5 = 0;
    float mx = 0.f;
    for (int nn = 0; nn < 64; ++nn) {
        float o = O[(size_t)(n0 + nn) * CC + c];
        a0 += o * sT[nn][0]; a1 += o * sT[nn][1]; a2 += o * sT[nn][2];
        a3 += o * sT[nn][3]; a4 += o * sT[nn][4]; a5 += o * sT[nn][5];
        mx = fmaxf(mx, o);
    }
    atomicAdd(&M[0 * CC + c], a0);
    atomicAdd(&M[1 * CC + c], a1);
    atomicAdd(&M[2 * CC + c], a2);
    atomicAdd(&M[3 * CC + c], a3);
    atomicAdd(&M[4 * CC + c], a4);
    atomicAdd(&M[5 * CC + c], a5);
    atomicMax((int*)&dst[c], __float_as_int(mx));
}

__global__ __launch_bounds__(256) void fro_kernel(const float* __restrict__ M, float* __restrict__ dst) {
    __shared__ float red[256];
    int t = threadIdx.x;
    int i = blockIdx.x * 256 + t;
    float v = (i < 6 * CC) ? M[i] : 0.f;
    red[t] = v * v;
    __syncthreads();
    for (int o = 128; o; o >>= 1) { if (t < o) red[t] += red[t + o]; __syncthreads(); }
    if (t == 0) atomicAdd(dst, red[0]);
}

// ---------------- pooling ----------------

__global__ __launch_bounds__(256) void vfr_kernel(const float* __restrict__ outF,
                                                  const int* __restrict__ sccs,
                                                  float* __restrict__ vfr) {
    int r = blockIdx.y;
    int c = blockIdx.x * 256 + threadIdx.x;
    if (c >= CC) return;
    int s0 = blockIdx.z * 41;
    float m = 0.f;
    for (int s = s0; s < s0 + 41; ++s) {
        int n = sccs[r * SSC + s];
        m = fmaxf(m, outF[(size_t)n * CC + c]);
    }
    atomicMax((int*)&vfr[(size_t)r * CC + c], __float_as_int(m));
}

// ---------------- reeb branch ----------------

__global__ __launch_bounds__(256) void reeb_mm_kernel(const float* __restrict__ Lr,
                                                      const float* __restrict__ Vin,
                                                      const float* __restrict__ Vsub,
                                                      float* __restrict__ Vout, float a2) {
    int c = blockIdx.x * 256 + threadIdx.x;
    if (c >= CC) return;
    int r = blockIdx.y;
    float s = 0.f;
#pragma unroll
    for (int j = 0; j < NRB; ++j) s += Lr[r * NRB + j] * Vin[(size_t)j * CC + c];
    float v = a2 * s;
    if (Vsub) v -= Vsub[(size_t)r * CC + c];
    Vout[(size_t)r * CC + c] = v;
}

#define RKC 25
__global__ __launch_bounds__(256) void reeb_conv_splitk(const float* __restrict__ vfr,
                                                        const float* __restrict__ tr1,
                                                        const float* __restrict__ tr2,
                                                        const float* __restrict__ Wr,
                                                        float* __restrict__ rpre) {
    __shared__ float sA[NRB][RKC];
    int t = threadIdx.x;
    int kbase = blockIdx.y * RKC;
    for (int i = t; i < NRB * RKC; i += 256) {
        int r = i / RKC, kk = i % RKC;
        int kg = kbase + kk;
        float v;
        if (kg < CC)           v = vfr[(size_t)r * CC + kg];
        else if (kg < 2 * CC)  v = tr1[(size_t)r * CC + kg - CC];
        else                   v = tr2[(size_t)r * CC + kg - 2 * CC];
        sA[r][kk] = v;
    }
    __syncthreads();
    int c = blockIdx.x * 256 + t;
    if (c >= CC) return;
    float acc[NRB];
#pragma unroll
    for (int r = 0; r < NRB; ++r) acc[r] = 0.f;
    for (int kk = 0; kk < RKC; ++kk) {
        float wv = Wr[(size_t)(kbase + kk) * CC + c];
#pragma unroll
        for (int r = 0; r < NRB; ++r) acc[r] += sA[r][kk] * wv;
    }
#pragma unroll
    for (int r = 0; r < NRB; ++r) atomicAdd(&rpre[(size_t)r * CC + c], acc[r]);
}

__global__ __launch_bounds__(256) void reeb_max_kernel(const float* __restrict__ pre,
                                                       const float* __restrict__ br,
                                                       float* __restrict__ rbm) {
    int c = blockIdx.x * 256 + threadIdx.x;
    if (c >= CC) return;
    float bb = br[c];
    float m = 0.f;
    for (int r = 0; r < NRB; ++r) m = fmaxf(m, fmaxf(pre[(size_t)r * CC + c] + bb, 0.f));
    rbm[c] = m;
}

// ---------------- FC head ----------------

__global__ __launch_bounds__(256) void fc1_kernel(const float* __restrict__ rbm,
                                                  const float* __restrict__ otm,
                                                  const float* __restrict__ w,
                                                  float* __restrict__ h1pre) {
    int j = blockIdx.x * 256 + threadIdx.x;
    if (j >= 512) return;
    int i0 = blockIdx.y * 250;
    float s = 0.f;
    for (int i = i0; i < i0 + 250; ++i) {
        float v = (i < CC) ? rbm[i] : otm[i - CC];
        s += v * w[(size_t)i * 512 + j];
    }
    atomicAdd(&h1pre[j], s);
}

__global__ __launch_bounds__(512) void fc23_kernel(const float* __restrict__ h1pre,
                                                   const float* __restrict__ b1f,
                                                   const float* __restrict__ w2,
                                                   const float* __restrict__ b2f,
                                                   const float* __restrict__ w3,
                                                   const float* __restrict__ b3f,
                                                   float* __restrict__ dout) {
    __shared__ float h1[512];
    __shared__ float h2[128];
    int t = threadIdx.x;
    h1[t] = fmaxf(h1pre[t] + b1f[t], 0.f);
    __syncthreads();
    if (t < 128) {
        float s = b2f[t];
        for (int i = 0; i < 512; ++i) s += h1[i] * w2[(size_t)i * 128 + t];
        h2[t] = fmaxf(s, 0.f);
    }
    __syncthreads();
    if (t < 40) {
        float s = b3f[t];
        for (int i = 0; i < 128; ++i) s += h2[i] * w3[(size_t)i * 40 + t];
        dout[t] = s;
    }
}

__global__ __launch_bounds__(256) void finalize_kernel(const float* __restrict__ racc,
                                                       const float* __restrict__ f1w,
                                                       const float* __restrict__ f1b,
                                                       const float* __restrict__ f2w,
                                                       const float* __restrict__ f2b,
                                                       const float* __restrict__ f3w,
                                                       const float* __restrict__ f3b,
                                                       float* __restrict__ dout) {
    __shared__ float red[256];
    __shared__ float res[3];
    int t = threadIdx.x;
    float s1 = 0.f, s2 = 0.f, s3 = 0.f;
    for (int i = t; i < 2000; i += 256) { float v = f1w[(size_t)i * 512]; s1 += v * v; }
    for (int i = t; i < 512; i += 256) { float v = f2w[(size_t)i * 128]; s2 += v * v; }
    if (t < 128) { float v = f3w[(size_t)t * 40]; s3 = v * v; }

    red[t] = s1; __syncthreads();
    for (int o = 128; o; o >>= 1) { if (t < o) red[t] += red[t + o]; __syncthreads(); }
    if (t == 0) res[0] = red[0];
    __syncthreads();
    red[t] = s2; __syncthreads();
    for (int o = 128; o; o >>= 1) { if (t < o) red[t] += red[t + o]; __syncthreads(); }
    if (t == 0) res[1] = red[0];
    __syncthreads();
    red[t] = s3; __syncthreads();
    for (int o = 128; o; o >>= 1) { if (t < o) red[t] += red[t + o]; __syncthreads(); }
    if (t == 0) res[2] = red[0];
    __syncthreads();

    if (t == 0) {
        dout[40] = sqrtf(racc[0]);
        dout[41] = sqrtf(racc[1]);
        dout[42] = res[0];
        dout[43] = f1b[0] * f1b[0];
        dout[44] = res[1];
        dout[45] = f2b[0] * f2b[0];
        dout[46] = res[2];
        dout[47] = f3b[0] * f3b[0];
    }
}

// ---------------- host ----------------

extern "C" void kernel_launch(void* const* d_in, const int* in_sizes, int n_in,
                              void* d_out, int out_size, void* d_ws, size_t ws_size,
                              hipStream_t stream) {
    const float* x    = (const float*)d_in[0];
    const float* Lr   = (const float*)d_in[5];
    const int*   sccs = (const int*)d_in[6];
    const float* W1   = (const float*)d_in[7];
    const float* b1   = (const float*)d_in[8];
    const float* W2   = (const float*)d_in[9];
    const float* b2   = (const float*)d_in[10];
    const float* Wr   = (const float*)d_in[11];
    const float* br   = (const float*)d_in[12];
    const float* f1w  = (const float*)d_in[13];
    const float* f1b  = (const float*)d_in[14];
    const float* f2w  = (const float*)d_in[15];
    const float* f2b  = (const float*)d_in[16];
    const float* f3w  = (const float*)d_in[17];
    const float* f3b  = (const float*)d_in[18];
    float* dout = (float*)d_out;

    char* ws = (char*)d_ws;
    size_t off = 0;
    auto alloc = [&](size_t bytes) -> char* {
        char* p = ws + off;
        off = (off + bytes + 255) & ~(size_t)255;
        return p;
    };
    float* outF = (float*)alloc((size_t)N4 * CC * 4);             // graph1 out, then reused as out2
    unsigned short* Cpb = (unsigned short*)alloc((size_t)6 * N4 * CC * 2);  // bf16 split-K partials
    unsigned short* Sb  = (unsigned short*)alloc((size_t)N4 * N4 * 2);      // bf16 distances
    unsigned short* Tall = (unsigned short*)alloc((size_t)N4 * KP6 * 2);
    unsigned short* W2T6 = Sb;   // alias: Sb dead after topk2
    float* xhat = (float*)alloc((size_t)N4 * 18 * 4);
    float* sq1  = (float*)alloc(N4 * 4);
    float* sq2  = (float*)alloc(N4 * 4);
    float* rs1  = (float*)alloc(N4 * 4);
    float* rs2  = (float*)alloc(N4 * 4);
    float* wv1  = (float*)alloc((size_t)N4 * KNN * 4);
    float* wv2  = (float*)alloc((size_t)N4 * KNN * 4);
    int*   ix1  = (int*)alloc((size_t)N4 * KNN * 4);
    int*   ix2  = (int*)alloc((size_t)N4 * KNN * 4);
    float* t2x  = (float*)alloc((size_t)N4 * FDIM * 4);
    float* tr1  = (float*)alloc((size_t)NRB * CC * 4);
    float* tr2  = (float*)alloc((size_t)NRB * CC * 4);
    char*  zbase = ws + off;
    float* Mb   = (float*)alloc(6 * CC * 4);
    float* Mb2  = (float*)alloc(6 * CC * 4);
    float* rbm  = (float*)alloc(CC * 4);
    float* otm  = (float*)alloc(CC * 4);
    float* h1p  = (float*)alloc(512 * 4);
    float* racc = (float*)alloc(64 * 4);
    float* rpre = (float*)alloc((size_t)NRB * CC * 4);
    float* vfr  = (float*)alloc((size_t)NRB * CC * 4);
    size_t zlen = (size_t)((ws + off) - zbase);
    if (off > ws_size) return;

    hipMemsetAsync(zbase, 0, zlen, stream);

    // ---- graph 1 (on x): fused distance + top-40 ----
    sqx_kernel<<<(N4 + 255) / 256, 256, 0, stream>>>(x, sq1, xhat);
    topk_fused1<<<N4, 512, 0, stream>>>(x, sq1, ix1, wv1, rs1);
    wnorm_kernel<<<(N4 * KNN + 255) / 256, 256, 0, stream>>>(wv1, ix1, rs1);

    // ---- cheb conv 1 (fused: fp32 out + bf16 Tall slice 0 + sq2 rowsums) ----
    spmv_cheb<<<N4, 64, 0, stream>>>(xhat, xhat, xhat + 6, ix1, wv1, FDIM, 18, 18, 18, 1.f, 0.f);
    spmv_cheb<<<N4, 64, 0, stream>>>(xhat + 6, xhat, xhat + 12, ix1, wv1, FDIM, 18, 18, 18, 2.f, 1.f);
    cheb1_out_kernel<<<N4 / 16, 256, 0, stream>>>(xhat, W1, b1, outF, Tall, sq2);

    matT6_partial<<<dim3(4, 64), 256, 0, stream>>>(outF, xhat + 6, 18, Mb);
    fro_kernel<<<24, 256, 0, stream>>>(Mb, racc + 0);

    vfr_kernel<<<dim3(4, NRB, 5), 256, 0, stream>>>(outF, sccs, vfr);

    // ---- graph 2 (on outF) ----
    gram2_mfma<<<dim3(N4 / 128, N4 / 256), 256, 0, stream>>>(Tall, sq2, Sb);
    topk_radix<<<N4, 512, 0, stream>>>(Sb, ix2, wv2, rs2);
    wnorm_kernel<<<(N4 * KNN + 255) / 256, 256, 0, stream>>>(wv2, ix2, rs2);

    // Sb dead -> build W2T6 in its space
    w2t_kernel<<<dim3(16, 16, 6), 256, 0, stream>>>(W2, W2T6);

    spmv_cheb<<<N4, 64, 0, stream>>>(x, x, t2x, ix2, wv2, FDIM, FDIM, FDIM, FDIM, 1.f, 0.f);

    // ---- cheb recursion (bf16, into Tall slices 1..5; col-split for L2 residency) ----
    spmv_cheb_bf<<<dim3(N4, 2), 256, 0, stream>>>(Tall + 0 * KP, Tall + 0 * KP, Tall + 1 * KP, ix2, wv2, 1.f, 0.f);
    spmv_cheb_bf<<<dim3(N4, 2), 256, 0, stream>>>(Tall + 1 * KP, Tall + 0 * KP, Tall + 2 * KP, ix2, wv2, 2.f, 1.f);
    spmv_cheb_bf<<<dim3(N4, 2), 256, 0, stream>>>(Tall + 2 * KP, Tall + 1 * KP, Tall + 3 * KP, ix2, wv2, 2.f, 1.f);
    spmv_cheb_bf<<<dim3(N4, 2), 256, 0, stream>>>(Tall + 3 * KP, Tall + 2 * KP, Tall + 4 * KP, ix2, wv2, 2.f, 1.f);
    spmv_cheb_bf<<<dim3(N4, 2), 256, 0, stream>>>(Tall + 4 * KP, Tall + 3 * KP, Tall + 5 * KP, ix2, wv2, 2.f, 1.f);

    // ---- batched K=6144 GEMM (split-K=3, BK=64, bf16 partials, 128-tiles) ----
    gemm_mfma_big<<<dim3(N4 / 128, 8, 3), 256, 0, stream>>>(Tall, W2T6, Cpb);
    bias_relu_merge<<<(int)(((size_t)N4 * CC / 8 + 255) / 256), 256, 0, stream>>>(Cpb, b2, outF);

    // matT6 + colmax fused: one pass over out2
    matT6_colmax<<<dim3(4, 64), 256, 0, stream>>>(outF, t2x, FDIM, Mb2, otm);
    fro_kernel<<<24, 256, 0, stream>>>(Mb2, racc + 1);

    // ---- reeb cheb conv (K=3) ----
    reeb_mm_kernel<<<dim3(4, NRB), 256, 0, stream>>>(Lr, vfr, nullptr, tr1, 1.f);
    reeb_mm_kernel<<<dim3(4, NRB), 256, 0, stream>>>(Lr, tr1, vfr, tr2, 2.f);
    reeb_conv_splitk<<<dim3(4, 120), 256, 0, stream>>>(vfr, tr1, tr2, Wr, rpre);
    reeb_max_kernel<<<4, 256, 0, stream>>>(rpre, br, rbm);

    // ---- FC head ----
    fc1_kernel<<<dim3(2, 8), 256, 0, stream>>>(rbm, otm, f1w, h1p);
    fc23_kernel<<<1, 512, 0, stream>>>(h1p, f1b, f2w, f2b, f3w, f3b, dout);
    finalize_kernel<<<1, 256, 0, stream>>>(racc, f1w, f1b, f2w, f2b, f3w, f3b, dout);
}